// Round 13
// baseline (588.222 us; speedup 1.0000x reference)
//
#include <hip/hip_runtime.h>
#include <math.h>

#define NN 10000
#define NE 320000
#define NODE_F 64
#define EDGE_F 32
#define HDIM 256
#define HEADS 8
#define LAYERS 6
#define NG 16
#define NOUT 48 // LAYERS*HEADS
#define LOG2E 1.4426950408889634f

typedef __attribute__((ext_vector_type(8))) short short8;
typedef __attribute__((ext_vector_type(4))) float float4v;
typedef __attribute__((ext_vector_type(2))) float floatx2;

// ---------------------------------------------------------------- CSR scan
// shuffle-based scan: 1024 threads, 2 barriers total
__global__ void scan_kernel(const int* __restrict__ cnt, int* __restrict__ row_ptr,
                            int* __restrict__ pos) {
    __shared__ int wsum[16];
    __shared__ int woff[16];
    int t = threadIdx.x;
    int lane = t & 63, wid = t >> 6;
    const int chunk = 10;                 // 1024*10 >= NN
    int lo = t * chunk;
    int loc[10];
    int s = 0;
    #pragma unroll
    for (int k = 0; k < 10; ++k) {
        int i = lo + k;
        int v = (i < NN) ? cnt[i] : 0;
        loc[k] = v;
        s += v;
    }
    int inc = s;
    #pragma unroll
    for (int off = 1; off < 64; off <<= 1) {
        int v = __shfl_up(inc, off, 64);
        if (lane >= off) inc += v;
    }
    if (lane == 63) wsum[wid] = inc;
    __syncthreads();
    if (t < 16) {
        int inc2 = wsum[t];
        #pragma unroll
        for (int off = 1; off < 16; off <<= 1) {
            int u = __shfl_up(inc2, off, 16);
            if (t >= off) inc2 += u;
        }
        woff[t] = inc2;
    }
    __syncthreads();
    int base = inc - s + (wid ? woff[wid - 1] : 0);
    #pragma unroll
    for (int k = 0; k < 10; ++k) {
        int i = lo + k;
        if (i < NN) {
            row_ptr[i] = base;
            pos[i] = base;
            base += loc[k];
        }
    }
    if (t == 1023) row_ptr[NN] = woff[15];
}

// index-only CSR scatter: csr_se[idx] = {src[e], e}. 8B random writes into a
// 2.56 MB (L2-resident) buffer — payloads are NOT permuted.
__global__ void scatter_kernel(const int* __restrict__ src, const int* __restrict__ dst,
                               int* __restrict__ pos, int2* __restrict__ csr_se) {
    int e = blockIdx.x * 256 + threadIdx.x;
    if (e >= NE) return;
    int d = dst[e];
    int idx = atomicAdd(&pos[d], 1);
    csr_se[idx] = make_int2(src[e], e);
}

// ---------------------------------------------------------------- bf16 helpers
__device__ __forceinline__ ushort f2bf(float f) {
    union { float f; unsigned u; } v; v.f = f;
    unsigned u = v.u;
    return (ushort)((u + 0x7fffu + ((u >> 16) & 1u)) >> 16);
}
__device__ __forceinline__ float bf2f(ushort b) {
    union { unsigned u; float f; } v; v.u = ((unsigned)b) << 16; return v.f;
}

// ---------------------------------------------------------------- edge-attn weight folding
// Fused fold + bf16 conversion, LOG2E-scaled so downstream softmax uses exp2.
__global__ __launch_bounds__(256) void prep_kernel(const float* __restrict__ att_edge,
                                                   const float* __restrict__ lin_edge_w,
                                                   const float* __restrict__ eew,
                                                   const float* __restrict__ eeb,
                                                   ushort* __restrict__ webbf,
                                                   float* __restrict__ bebuf) {
    int ih = blockIdx.x;            // i*HEADS + h
    int i = ih >> 3, h = ih & 7;
    __shared__ float vsh[HDIM];
    int t = threadIdx.x;
    float s = 0.f;
    const float* ae = att_edge + ih * 32;
    const float* lw = lin_edge_w + ((size_t)i * HDIM + h * 32) * HDIM + t;
    #pragma unroll
    for (int o = 0; o < 32; ++o) s += ae[o] * lw[(size_t)o * HDIM];
    vsh[t] = s;
    __syncthreads();
    if (t < EDGE_F) {
        float acc = 0.f;
        for (int k = 0; k < HDIM; ++k) acc += vsh[k] * eew[k * EDGE_F + t];
        webbf[ih * EDGE_F + t] = f2bf(acc * LOG2E);
    } else if (t == EDGE_F) {
        float acc = 0.f;
        for (int k = 0; k < HDIM; ++k) acc += vsh[k] * eeb[k];
        bebuf[ih] = acc * LOG2E;
    }
}

// ---------------------------------------------------------------- embedding fold
// W0p = lin_w[0] @ node_w  (HDIM x NODE_F, bf16), b0p = lin_w[0] @ node_b.
// Exact algebra: xw0 = (x@node_w.T + node_b)@W1.T = x@W0p.T + b0p.
__global__ __launch_bounds__(64) void fold0_kernel(const float* __restrict__ lin_w,
                                                   const float* __restrict__ node_w,
                                                   const float* __restrict__ node_b,
                                                   ushort* __restrict__ w0p,
                                                   float* __restrict__ b0p) {
    int j = blockIdx.x, f = threadIdx.x;   // 256 blocks x 64 threads
    const float* wr = lin_w + (size_t)j * HDIM;
    float acc = 0.f, accb = 0.f;
    for (int k = 0; k < HDIM; ++k) acc += wr[k] * node_w[k * NODE_F + f];
    #pragma unroll
    for (int m = 0; m < 4; ++m) {
        int k = f + 64 * m;
        accb += wr[k] * node_b[k];
    }
    w0p[j * NODE_F + f] = f2bf(acc);
    #pragma unroll
    for (int off = 32; off >= 1; off >>= 1) accb += __shfl_xor(accb, off, 64);
    if (f == 0) b0p[j] = accb;
}

// ---------------------------------------------------------------- preE via MFMA (+ degree count)
// Pure streaming: read edge_attr in e-order (coalesced f32), write
// preE8[li][e][8] sequentially as fp8-e4m3 (LOG2E-scaled logits; small
// magnitudes -> small ABSOLUTE error, which is what exp2 cares about).
// Threads 0..63 also count in-degrees for the CSR build.
__global__ __launch_bounds__(256) void preE_kernel(const float* __restrict__ edge_attr,
                                                   const ushort* __restrict__ web,
                                                   const float* __restrict__ be,
                                                   unsigned char* __restrict__ preE8,
                                                   const int* __restrict__ dst,
                                                   int* __restrict__ cnt) {
    int t = threadIdx.x;
    if (t < 64) atomicAdd(&cnt[dst[blockIdx.x * 64 + t]], 1);
    int wv = t >> 6, l = t & 63;
    int base = blockIdx.x * 64 + wv * 16;   // NE % 64 == 0
    int m = l & 15, kq = (l >> 4) * 8;
    const float* ar = edge_attr + (size_t)(base + m) * EDGE_F + kq;
    float4 a0 = *(const float4*)(ar);
    float4 a1 = *(const float4*)(ar + 4);
    short8 afrag;
    afrag[0] = (short)f2bf(a0.x); afrag[1] = (short)f2bf(a0.y);
    afrag[2] = (short)f2bf(a0.z); afrag[3] = (short)f2bf(a0.w);
    afrag[4] = (short)f2bf(a1.x); afrag[5] = (short)f2bf(a1.y);
    afrag[6] = (short)f2bf(a1.z); afrag[7] = (short)f2bf(a1.w);
    float4v zero = {0.f, 0.f, 0.f, 0.f};
    float4v acc[3];
    #pragma unroll
    for (int ct = 0; ct < 3; ++ct) {
        short8 bfrag = *(const short8*)(web + (size_t)(ct * 16 + m) * EDGE_F + kq);
        acc[ct] = __builtin_amdgcn_mfma_f32_16x16x32_bf16(afrag, bfrag, zero, 0, 0, 0);
    }
    #pragma unroll
    for (int ct = 0; ct < 3; ++ct) {
        int oc = ct * 16 + m;
        int li = oc >> 3, hh = oc & 7;
        float bv = be[oc];
        #pragma unroll
        for (int r = 0; r < 4; ++r) {
            int row = (l >> 4) * 4 + r;
            float v = acc[ct][r] + bv;
            int pk8 = __builtin_amdgcn_cvt_pk_fp8_f32(v, v, 0, false);
            preE8[(size_t)li * NE * 8 + (size_t)(base + row) * 8 + hh] =
                (unsigned char)(pk8 & 0xff);
        }
    }
}

// ---------------------------------------------------------------- f32 -> bf16 (weights + x)
__global__ void tobf_all_kernel(const float* __restrict__ lin_w,
                                const float* __restrict__ x, ushort* __restrict__ wbhi,
                                ushort* __restrict__ xhi) {
    const int N1 = LAYERS * HDIM * HDIM;   // 393216
    const int N2 = N1 + NN * NODE_F;       // 1033216
    int i = blockIdx.x * 256 + threadIdx.x;
    if (i < N1) wbhi[i] = f2bf(lin_w[i]);
    else if (i < N2) xhi[i - N1] = f2bf(x[i - N1]);
}

// ---------------------------------------------------------------- pure-bf16 MFMA GEMM
// Writes fp8-e4m3 message table + attention logit partials a_src/a_dst
// (LOG2E-scaled). Bias (if any) is folded into the accumulators BEFORE both
// epilogues so logits include it exactly. Each 64-col block covers exactly
// 2 complete heads -> no atomics.
__global__ __launch_bounds__(128) void gemm_bf1(const ushort* __restrict__ Ah,
                                                const ushort* __restrict__ Bh,
                                                const float* __restrict__ bias,
                                                unsigned char* __restrict__ Cf8,
                                                const float* __restrict__ att_s,
                                                const float* __restrict__ att_d,
                                                float* __restrict__ a_src,
                                                float* __restrict__ a_dst,
                                                int N, int K) {
    __shared__ ushort sAh[64][40], sBh[64][40];
    int nb = blockIdx.y * 64, jb = blockIdx.x * 64;
    int t = threadIdx.x, w = t >> 6, l = t & 63;
    int srow = t >> 1, sq = (t & 1) * 16;
    int fr = l & 15, fq = (l >> 4) * 8;
    float4v acc[2][4] = {};
    for (int kt = 0; kt < K; kt += 32) {
        int gr = nb + srow;
        short8 a0 = {0,0,0,0,0,0,0,0}, a1 = {0,0,0,0,0,0,0,0};
        if (gr < N) {
            const short8* pa = (const short8*)(Ah + (size_t)gr * K + kt + sq);
            a0 = pa[0]; a1 = pa[1];
        }
        *(short8*)&sAh[srow][sq] = a0; *(short8*)&sAh[srow][sq + 8] = a1;
        const short8* pb = (const short8*)(Bh + (size_t)(jb + srow) * K + kt + sq);
        short8 b0 = pb[0], b1 = pb[1];
        *(short8*)&sBh[srow][sq] = b0; *(short8*)&sBh[srow][sq + 8] = b1;
        __syncthreads();
        short8 bh[4];
        #pragma unroll
        for (int nt = 0; nt < 4; ++nt)
            bh[nt] = *(const short8*)&sBh[nt * 16 + fr][fq];
        #pragma unroll
        for (int mt = 0; mt < 2; ++mt) {
            short8 ah = *(const short8*)&sAh[w * 32 + mt * 16 + fr][fq];
            #pragma unroll
            for (int nt = 0; nt < 4; ++nt)
                acc[mt][nt] = __builtin_amdgcn_mfma_f32_16x16x32_bf16(ah, bh[nt], acc[mt][nt], 0, 0, 0);
        }
        __syncthreads();
    }
    if (bias) {
        #pragma unroll
        for (int nt = 0; nt < 4; ++nt) {
            float bv = bias[jb + nt * 16 + fr];
            #pragma unroll
            for (int mt = 0; mt < 2; ++mt)
                #pragma unroll
                for (int r = 0; r < 4; ++r) acc[mt][nt][r] += bv;
        }
    }
    #pragma unroll
    for (int mt = 0; mt < 2; ++mt) {
        #pragma unroll
        for (int nt = 0; nt < 4; ++nt) {
            int col = jb + nt * 16 + fr;
            #pragma unroll
            for (int r = 0; r < 4; ++r) {
                int row = nb + w * 32 + mt * 16 + (l >> 4) * 4 + r;
                if (row < N) {
                    float v = acc[mt][nt][r];
                    int pk8 = __builtin_amdgcn_cvt_pk_fp8_f32(v, v, 0, false);
                    Cf8[(size_t)row * HDIM + col] = (unsigned char)(pk8 & 0xff);
                }
            }
        }
    }
    {
        int head0 = jb >> 5;
        float cs[4], cd[4];
        #pragma unroll
        for (int nt = 0; nt < 4; ++nt) {
            cs[nt] = att_s[jb + nt * 16 + fr] * LOG2E;
            cd[nt] = att_d[jb + nt * 16 + fr] * LOG2E;
        }
        #pragma unroll
        for (int mt = 0; mt < 2; ++mt) {
            #pragma unroll
            for (int r = 0; r < 4; ++r) {
                float s0 = acc[mt][0][r] * cs[0] + acc[mt][1][r] * cs[1];
                float s1 = acc[mt][2][r] * cs[2] + acc[mt][3][r] * cs[3];
                float d0 = acc[mt][0][r] * cd[0] + acc[mt][1][r] * cd[1];
                float d1 = acc[mt][2][r] * cd[2] + acc[mt][3][r] * cd[3];
                #pragma unroll
                for (int off = 8; off >= 1; off >>= 1) {
                    s0 += __shfl_xor(s0, off, 16);
                    s1 += __shfl_xor(s1, off, 16);
                    d0 += __shfl_xor(d0, off, 16);
                    d1 += __shfl_xor(d1, off, 16);
                }
                if (fr == 0) {
                    int row = nb + w * 32 + mt * 16 + (l >> 4) * 4 + r;
                    if (row < N) {
                        a_src[row * 8 + head0]     = s0;
                        a_src[row * 8 + head0 + 1] = s1;
                        a_dst[row * 8 + head0]     = d0;
                        a_dst[row * 8 + head0 + 1] = d1;
                    }
                }
            }
        }
    }
}

__device__ __forceinline__ float gelu_exact(float x) {
    return 0.5f * x * (1.f + erff(x * 0.70710678118654752f));
}

// ---------------------------------------------------------------- fused single-pass node kernel
// ONE NODE PER 128-THREAD BLOCK, edge range split across 2 waves (interleaved
// 8-edge groups); partial den/acc/psum combined via one LDS exchange + barrier.
// fp8 message table AND fp8 logit table (both L2-resident), transposed logit
// computation, in-register preL, bf16 residual stream.
__global__ __launch_bounds__(128) void node_kernel(const unsigned char* __restrict__ xwf8,
                                                  const unsigned char* __restrict__ pb,
                                                  const float* __restrict__ a_src,
                                                  const float* __restrict__ a_dst,
                                                  const int* __restrict__ row_ptr,
                                                  const int2* __restrict__ csr_se,
                                                  const ushort* __restrict__ hp,
                                                  ushort* __restrict__ hout,
                                                  const float* __restrict__ cb,
                                                  const float* __restrict__ lg,
                                                  const float* __restrict__ lb, int first) {
    __shared__ float red[6][128];
    int t = threadIdx.x;
    int wv = t >> 6, l = t & 63;
    int n = blockIdx.x;
    int start = row_ptr[n], end = row_ptr[n + 1];
    int hc = l >> 3;
    int hc8 = l & 56;
    int jj = l & 7;
    float adnh = a_dst[n * 8 + hc];
    const unsigned char* xb = xwf8 + 4 * l;

    float den = 0.f, acc[4] = {0.f, 0.f, 0.f, 0.f};
    float psum = 0.f;
    for (int idx = start + wv * 8; idx < end; idx += 16) {
        int myi = idx + jj;
        bool valid = myi < end;
        int2 se = valid ? csr_se[myi] : make_int2(n, 0);
        int snj[8];
        #pragma unroll
        for (int j = 0; j < 8; ++j) snj[j] = __shfl(se.x, hc8 + j, 64);
        unsigned g[8];
        #pragma unroll
        for (int j = 0; j < 8; ++j) g[j] = *(const unsigned*)(xb + (size_t)snj[j] * HDIM);
        float w_t = 0.f;
        if (valid) {
            unsigned pu = pb[(size_t)se.y * 8 + hc];
            floatx2 pd = __builtin_amdgcn_cvt_pk_f32_fp8(pu, false);
            float p_t = pd.x;
            float a_t = a_src[(size_t)se.x * 8 + hc] + adnh + p_t;
            w_t = exp2f(fminf(fmaxf(a_t, 0.2f * a_t), 57.7f));
            psum += p_t;
        }
        #pragma unroll
        for (int j = 0; j < 8; ++j) {
            float wj = __shfl(w_t, hc8 + j, 64);
            floatx2 lo = __builtin_amdgcn_cvt_pk_f32_fp8(g[j], false);
            floatx2 hi = __builtin_amdgcn_cvt_pk_f32_fp8(g[j], true);
            den += wj;
            acc[0] += wj * lo.x;
            acc[1] += wj * lo.y;
            acc[2] += wj * hi.x;
            acc[3] += wj * hi.y;
        }
    }
    // per-wave psum reduce within each 8-lane head group
    #pragma unroll
    for (int off = 1; off < 8; off <<= 1) psum += __shfl_xor(psum, off, 64);
    // cross-wave combine (one LDS exchange)
    red[0][t] = den; red[1][t] = acc[0]; red[2][t] = acc[1];
    red[3][t] = acc[2]; red[4][t] = acc[3]; red[5][t] = psum;
    __syncthreads();
    int ot = t ^ 64;
    den += red[0][ot]; acc[0] += red[1][ot]; acc[1] += red[2][ot];
    acc[2] += red[3][ot]; acc[3] += red[4][ot]; psum += red[5][ot];

    int deg = end - start;
    float preLv = deg > 0 ? psum / (float)deg : 0.f;
    // self loop (after combine, computed redundantly by both waves)
    {
        float al = a_src[n * 8 + hc] + adnh + preLv;
        al = fminf(fmaxf(al, 0.2f * al), 57.7f);
        float wself = exp2f(al);
        den += wself;
        unsigned gs = *(const unsigned*)(xb + (size_t)n * HDIM);
        floatx2 lo = __builtin_amdgcn_cvt_pk_f32_fp8(gs, false);
        floatx2 hi = __builtin_amdgcn_cvt_pk_f32_fp8(gs, true);
        acc[0] += wself * lo.x;
        acc[1] += wself * lo.y;
        acc[2] += wself * hi.x;
        acc[3] += wself * hi.y;
    }
    float4 cb4 = *(const float4*)(cb + 4 * l);
    float invh = 1.f / (den + 1e-16f);
    acc[0] = acc[0] * invh + cb4.x;
    acc[1] = acc[1] * invh + cb4.y;
    acc[2] = acc[2] * invh + cb4.z;
    acc[3] = acc[3] * invh + cb4.w;

    // LayerNorm over 256 channels (within each wave; both waves hold identical state)
    float part = acc[0] + acc[1] + acc[2] + acc[3];
    #pragma unroll
    for (int off = 32; off >= 1; off >>= 1) part += __shfl_xor(part, off, 64);
    float mu = part * (1.f / 256.f);
    float p2 = 0.f;
    #pragma unroll
    for (int j = 0; j < 4; ++j) {
        float d = acc[j] - mu;
        p2 += d * d;
    }
    #pragma unroll
    for (int off = 32; off >= 1; off >>= 1) p2 += __shfl_xor(p2, off, 64);
    float rstd = rsqrtf(p2 * (1.f / 256.f) + 1e-5f);

    if (wv == 0) {
        float4 lg4 = *(const float4*)(lg + 4 * l);
        float4 lb4 = *(const float4*)(lb + 4 * l);
        float o4[4];
        float lgv[4] = {lg4.x, lg4.y, lg4.z, lg4.w};
        float lbv[4] = {lb4.x, lb4.y, lb4.z, lb4.w};
        float hpv[4] = {0.f, 0.f, 0.f, 0.f};
        if (!first) {
            uint2 ph = *(const uint2*)(hp + (size_t)n * HDIM + 4 * l);
            hpv[0] = bf2f((ushort)(ph.x & 0xffff));
            hpv[1] = bf2f((ushort)(ph.x >> 16));
            hpv[2] = bf2f((ushort)(ph.y & 0xffff));
            hpv[3] = bf2f((ushort)(ph.y >> 16));
        }
        #pragma unroll
        for (int j = 0; j < 4; ++j) {
            float y = (acc[j] - mu) * rstd * lgv[j] + lbv[j];
            o4[j] = gelu_exact(y) + hpv[j];
        }
        uint2 po;
        po.x = (unsigned)f2bf(o4[0]) | ((unsigned)f2bf(o4[1]) << 16);
        po.y = (unsigned)f2bf(o4[2]) | ((unsigned)f2bf(o4[3]) << 16);
        *(uint2*)(hout + (size_t)n * HDIM + 4 * l) = po;
    }
}

__device__ __forceinline__ int lower_bound_dev(const int* a, int n, int v) {
    int lo = 0, hi = n;
    while (lo < hi) {
        int mid = (lo + hi) >> 1;
        if (a[mid] < v) lo = mid + 1; else hi = mid;
    }
    return lo;
}

// fused graph readout + 3-layer MLP head: one block per (graph, which).
// batch is sorted, so graph g owns contiguous node range [s0,s1) found by
// binary search; each block sums its own rows (coalesced bf16 reads, no atomics).
__global__ __launch_bounds__(256) void mlp_kernel(const ushort* __restrict__ h,
                                                  const int* __restrict__ batch,
                                                  const float* __restrict__ pw1,
                                                  const float* __restrict__ pb1,
                                                  const float* __restrict__ pw2,
                                                  const float* __restrict__ pb2,
                                                  const float* __restrict__ pw3,
                                                  const float* __restrict__ pb3,
                                                  const float* __restrict__ mw1,
                                                  const float* __restrict__ mb1,
                                                  const float* __restrict__ mw2,
                                                  const float* __restrict__ mb2,
                                                  const float* __restrict__ mw3,
                                                  const float* __restrict__ mb3,
                                                  float* __restrict__ out) {
    int g = blockIdx.x, which = blockIdx.y;
    const float* w1 = which ? mw1 : pw1; const float* b1 = which ? mb1 : pb1;
    const float* w2 = which ? mw2 : pw2; const float* b2 = which ? mb2 : pb2;
    const float* w3 = which ? mw3 : pw3; const float* b3 = which ? mb3 : pb3;
    __shared__ float xg[512];
    __shared__ float h1[256];
    __shared__ float h2[128];
    int t = threadIdx.x;
    int s0 = lower_bound_dev(batch, NN, g), s1 = lower_bound_dev(batch, NN, g + 1);
    float sv = 0.f;
    for (int n = s0; n < s1; ++n) sv += bf2f(h[(size_t)n * HDIM + t]);
    float cinv = 1.f / fmaxf((float)(s1 - s0), 1.f);
    xg[t] = sv * cinv;
    xg[256 + t] = sv;
    __syncthreads();
    {
        const float* wr = w1 + (size_t)t * 512;
        float acc = 0.f;
        #pragma unroll 8
        for (int k = 0; k < 512; k += 4) {
            float4 wv = *(const float4*)(wr + k);
            acc += wv.x * xg[k] + wv.y * xg[k + 1] + wv.z * xg[k + 2] + wv.w * xg[k + 3];
        }
        h1[t] = gelu_exact(acc + b1[t]);
    }
    __syncthreads();
    {
        int row = t >> 1, hf = t & 1;
        const float* wr = w2 + (size_t)row * 256 + hf * 128;
        const float* hx = h1 + hf * 128;
        float acc = 0.f;
        #pragma unroll 8
        for (int k = 0; k < 128; k += 4) {
            float4 wv = *(const float4*)(wr + k);
            acc += wv.x * hx[k] + wv.y * hx[k + 1] + wv.z * hx[k + 2] + wv.w * hx[k + 3];
        }
        acc += __shfl_xor(acc, 1, 64);
        if (hf == 0) h2[row] = gelu_exact(acc + b2[row]);
    }
    __syncthreads();
    if (t < 64) {
        float v0 = h2[t], v1 = h2[64 + t];
        #pragma unroll
        for (int o = 0; o < 3; ++o) {
            float p = w3[o * 128 + t] * v0 + w3[o * 128 + 64 + t] * v1;
            #pragma unroll
            for (int off = 32; off >= 1; off >>= 1) p += __shfl_xor(p, off, 64);
            if (t == 0) out[which * (NG * 3) + g * 3 + o] = 1.f / (1.f + expf(-(p + b3[o])));
        }
    }
}

// ---------------------------------------------------------------- launch
extern "C" void kernel_launch(void* const* d_in, const int* in_sizes, int n_in, void* d_out,
                              int out_size, void* d_ws, size_t ws_size, hipStream_t stream) {
    const float* x         = (const float*)d_in[0];
    const int*   ei        = (const int*)d_in[1];
    const int*   src       = ei;
    const int*   dst       = ei + NE;
    const float* edge_attr = (const float*)d_in[2];
    const int*   batch     = (const int*)d_in[3];
    const float* node_w    = (const float*)d_in[4];
    const float* node_b    = (const float*)d_in[5];
    const float* eew       = (const float*)d_in[6];
    const float* eeb       = (const float*)d_in[7];
    const float* lin_w     = (const float*)d_in[8];
    const float* att_src   = (const float*)d_in[9];
    const float* att_dst   = (const float*)d_in[10];
    const float* att_edge  = (const float*)d_in[11];
    const float* lin_edge_w= (const float*)d_in[12];
    const float* conv_b    = (const float*)d_in[13];
    const float* ln_g      = (const float*)d_in[14];
    const float* ln_b      = (const float*)d_in[15];
    const float* pw1 = (const float*)d_in[16]; const float* pb1 = (const float*)d_in[17];
    const float* pw2 = (const float*)d_in[18]; const float* pb2 = (const float*)d_in[19];
    const float* pw3 = (const float*)d_in[20]; const float* pb3 = (const float*)d_in[21];
    const float* mw1 = (const float*)d_in[22]; const float* mb1 = (const float*)d_in[23];
    const float* mw2 = (const float*)d_in[24]; const float* mb2 = (const float*)d_in[25];
    const float* mw3 = (const float*)d_in[26]; const float* mb3 = (const float*)d_in[27];
    float* out = (float*)d_out;

    float* wsf = (float*)d_ws;
    float* a_src     = wsf; wsf += (size_t)NN * HEADS;
    float* a_dst     = wsf; wsf += (size_t)NN * HEADS;
    float* bebuf     = wsf; wsf += 64;
    float* b0p       = wsf; wsf += HDIM;
    ushort* ubuf = (ushort*)wsf;
    ushort* webbf = ubuf; ubuf += (size_t)NOUT * EDGE_F;
    ushort* hb0  = ubuf; ubuf += (size_t)NN * HDIM;    // bf16 residual stream A
    ushort* hb1  = ubuf; ubuf += (size_t)NN * HDIM;    // bf16 residual stream B
    ushort* wbhi = ubuf; ubuf += (size_t)LAYERS * HDIM * HDIM;
    ushort* xhi  = ubuf; ubuf += (size_t)NN * NODE_F;
    ushort* w0p  = ubuf; ubuf += (size_t)HDIM * NODE_F;
    unsigned char* cbuf = (unsigned char*)ubuf;
    unsigned char* preE8 = cbuf; cbuf += (size_t)NE * NOUT;   // [LAYERS][NE][8] fp8
    unsigned char* xwf8  = cbuf; cbuf += (size_t)NN * HDIM;
    cbuf += ((size_t)cbuf & 7) ? (8 - ((size_t)cbuf & 7)) : 0;  // 8B-align
    int* ibuf    = (int*)cbuf;
    int* cnt     = ibuf; ibuf += NN + 16;
    int* row_ptr = ibuf; ibuf += NN + 16;
    int* pos     = ibuf; ibuf += NN + 16;
    int2* csr_se = (int2*)ibuf; ibuf += 2 * NE;      // offset even -> 8B aligned

    // memset covers cnt only (sums buffer eliminated)
    hipMemsetAsync(cnt, 0, (NN + 16) * sizeof(int), stream);

    // fold edge-attention weights (LOG2E-scaled); preE = streaming MFMA + fused degree count
    prep_kernel<<<LAYERS * HEADS, 256, 0, stream>>>(att_edge, lin_edge_w, eew, eeb, webbf, bebuf);
    preE_kernel<<<NE / 64, 256, 0, stream>>>(edge_attr, webbf, bebuf, preE8, dst, cnt);

    // CSR build (index-only)
    scan_kernel<<<1, 1024, 0, stream>>>(cnt, row_ptr, pos);
    scatter_kernel<<<(NE + 255) / 256, 256, 0, stream>>>(src, dst, pos, csr_se);

    // GEMM operand prep + embedding fold (W0p = lin_w[0]@node_w, b0p = lin_w[0]@node_b)
    {
        const int total = LAYERS * HDIM * HDIM + NN * NODE_F;
        tobf_all_kernel<<<(total + 255) / 256, 256, 0, stream>>>(lin_w, x, wbhi, xhi);
    }
    fold0_kernel<<<HDIM, 64, 0, stream>>>(lin_w, node_w, node_b, w0p, b0p);

    ushort* hb[2] = {hb0, hb1};
    for (int i = 0; i < LAYERS; ++i) {
        dim3 grid(HDIM / 64, (NN + 63) / 64);
        const ushort* Ain = (i == 0) ? xhi : hb[(i - 1) & 1];
        const ushort* Bin = (i == 0) ? w0p : wbhi + (size_t)i * HDIM * HDIM;
        int Kin = (i == 0) ? NODE_F : HDIM;
        const float* bias = (i == 0) ? b0p : nullptr;
        gemm_bf1<<<grid, 128, 0, stream>>>(Ain, Bin, bias, xwf8,
                                           att_src + i * HEADS * 32, att_dst + i * HEADS * 32,
                                           a_src, a_dst, NN, Kin);
        node_kernel<<<NN, 128, 0, stream>>>(
            xwf8, preE8 + (size_t)i * NE * 8, a_src, a_dst,
            row_ptr, csr_se, (i == 0) ? nullptr : hb[(i - 1) & 1], hb[i & 1],
            conv_b + i * HDIM, ln_g + i * HDIM, ln_b + i * HDIM, i == 0 ? 1 : 0);
    }

    {
        dim3 gm(NG, 2);
        mlp_kernel<<<gm, 256, 0, stream>>>(hb[(LAYERS - 1) & 1], batch,
                                           pw1, pb1, pw2, pb2, pw3, pb3,
                                           mw1, mb1, mw2, mb2, mw3, mb3, out);
    }
}

// Round 14
// 464.029 us; speedup vs baseline: 1.2676x; 1.2676x over previous
//
#include <hip/hip_runtime.h>
#include <math.h>

#define NN 10000
#define NE 320000
#define NODE_F 64
#define EDGE_F 32
#define HDIM 256
#define HEADS 8
#define LAYERS 6
#define NG 16
#define NOUT 48 // LAYERS*HEADS
#define LOG2E 1.4426950408889634f

typedef __attribute__((ext_vector_type(8))) short short8;
typedef __attribute__((ext_vector_type(4))) float float4v;
typedef __attribute__((ext_vector_type(2))) float floatx2;

// ---------------------------------------------------------------- CSR scan
// shuffle-based scan: 1024 threads, 2 barriers total
__global__ void scan_kernel(const int* __restrict__ cnt, int* __restrict__ row_ptr,
                            int* __restrict__ pos) {
    __shared__ int wsum[16];
    __shared__ int woff[16];
    int t = threadIdx.x;
    int lane = t & 63, wid = t >> 6;
    const int chunk = 10;                 // 1024*10 >= NN
    int lo = t * chunk;
    int loc[10];
    int s = 0;
    #pragma unroll
    for (int k = 0; k < 10; ++k) {
        int i = lo + k;
        int v = (i < NN) ? cnt[i] : 0;
        loc[k] = v;
        s += v;
    }
    int inc = s;
    #pragma unroll
    for (int off = 1; off < 64; off <<= 1) {
        int v = __shfl_up(inc, off, 64);
        if (lane >= off) inc += v;
    }
    if (lane == 63) wsum[wid] = inc;
    __syncthreads();
    if (t < 16) {
        int inc2 = wsum[t];
        #pragma unroll
        for (int off = 1; off < 16; off <<= 1) {
            int u = __shfl_up(inc2, off, 16);
            if (t >= off) inc2 += u;
        }
        woff[t] = inc2;
    }
    __syncthreads();
    int base = inc - s + (wid ? woff[wid - 1] : 0);
    #pragma unroll
    for (int k = 0; k < 10; ++k) {
        int i = lo + k;
        if (i < NN) {
            row_ptr[i] = base;
            pos[i] = base;
            base += loc[k];
        }
    }
    if (t == 1023) row_ptr[NN] = woff[15];
}

// index-only CSR scatter: csr_se[idx] = {src[e], e}. 8B random writes into a
// 2.56 MB (L2-resident) buffer — payloads are NOT permuted.
__global__ void scatter_kernel(const int* __restrict__ src, const int* __restrict__ dst,
                               int* __restrict__ pos, int2* __restrict__ csr_se) {
    int e = blockIdx.x * 256 + threadIdx.x;
    if (e >= NE) return;
    int d = dst[e];
    int idx = atomicAdd(&pos[d], 1);
    csr_se[idx] = make_int2(src[e], e);
}

// ---------------------------------------------------------------- bf16 helpers
__device__ __forceinline__ ushort f2bf(float f) {
    union { float f; unsigned u; } v; v.f = f;
    unsigned u = v.u;
    return (ushort)((u + 0x7fffu + ((u >> 16) & 1u)) >> 16);
}
__device__ __forceinline__ float bf2f(ushort b) {
    union { unsigned u; float f; } v; v.u = ((unsigned)b) << 16; return v.f;
}

// ---------------------------------------------------------------- edge-attn weight folding
// Fused fold + bf16 conversion, LOG2E-scaled so downstream softmax uses exp2.
__global__ __launch_bounds__(256) void prep_kernel(const float* __restrict__ att_edge,
                                                   const float* __restrict__ lin_edge_w,
                                                   const float* __restrict__ eew,
                                                   const float* __restrict__ eeb,
                                                   ushort* __restrict__ webbf,
                                                   float* __restrict__ bebuf) {
    int ih = blockIdx.x;            // i*HEADS + h
    int i = ih >> 3, h = ih & 7;
    __shared__ float vsh[HDIM];
    int t = threadIdx.x;
    float s = 0.f;
    const float* ae = att_edge + ih * 32;
    const float* lw = lin_edge_w + ((size_t)i * HDIM + h * 32) * HDIM + t;
    #pragma unroll
    for (int o = 0; o < 32; ++o) s += ae[o] * lw[(size_t)o * HDIM];
    vsh[t] = s;
    __syncthreads();
    if (t < EDGE_F) {
        float acc = 0.f;
        for (int k = 0; k < HDIM; ++k) acc += vsh[k] * eew[k * EDGE_F + t];
        webbf[ih * EDGE_F + t] = f2bf(acc * LOG2E);
    } else if (t == EDGE_F) {
        float acc = 0.f;
        for (int k = 0; k < HDIM; ++k) acc += vsh[k] * eeb[k];
        bebuf[ih] = acc * LOG2E;
    }
}

// ---------------------------------------------------------------- embedding fold
// W0p = lin_w[0] @ node_w  (HDIM x NODE_F, bf16), b0p = lin_w[0] @ node_b.
// Exact algebra: xw0 = (x@node_w.T + node_b)@W1.T = x@W0p.T + b0p.
__global__ __launch_bounds__(64) void fold0_kernel(const float* __restrict__ lin_w,
                                                   const float* __restrict__ node_w,
                                                   const float* __restrict__ node_b,
                                                   ushort* __restrict__ w0p,
                                                   float* __restrict__ b0p) {
    int j = blockIdx.x, f = threadIdx.x;   // 256 blocks x 64 threads
    const float* wr = lin_w + (size_t)j * HDIM;
    float acc = 0.f, accb = 0.f;
    for (int k = 0; k < HDIM; ++k) acc += wr[k] * node_w[k * NODE_F + f];
    #pragma unroll
    for (int m = 0; m < 4; ++m) {
        int k = f + 64 * m;
        accb += wr[k] * node_b[k];
    }
    w0p[j * NODE_F + f] = f2bf(acc);
    #pragma unroll
    for (int off = 32; off >= 1; off >>= 1) accb += __shfl_xor(accb, off, 64);
    if (f == 0) b0p[j] = accb;
}

// ---------------------------------------------------------------- preE via MFMA (+ degree count)
// Pure streaming: read edge_attr in e-order (coalesced f32), write
// preE8[li][e][8] sequentially as fp8-e4m3 (LOG2E-scaled logits; small
// magnitudes -> small ABSOLUTE error, which is what exp2 cares about).
// Threads 0..63 also count in-degrees for the CSR build.
__global__ __launch_bounds__(256) void preE_kernel(const float* __restrict__ edge_attr,
                                                   const ushort* __restrict__ web,
                                                   const float* __restrict__ be,
                                                   unsigned char* __restrict__ preE8,
                                                   const int* __restrict__ dst,
                                                   int* __restrict__ cnt) {
    int t = threadIdx.x;
    if (t < 64) atomicAdd(&cnt[dst[blockIdx.x * 64 + t]], 1);
    int wv = t >> 6, l = t & 63;
    int base = blockIdx.x * 64 + wv * 16;   // NE % 64 == 0
    int m = l & 15, kq = (l >> 4) * 8;
    const float* ar = edge_attr + (size_t)(base + m) * EDGE_F + kq;
    float4 a0 = *(const float4*)(ar);
    float4 a1 = *(const float4*)(ar + 4);
    short8 afrag;
    afrag[0] = (short)f2bf(a0.x); afrag[1] = (short)f2bf(a0.y);
    afrag[2] = (short)f2bf(a0.z); afrag[3] = (short)f2bf(a0.w);
    afrag[4] = (short)f2bf(a1.x); afrag[5] = (short)f2bf(a1.y);
    afrag[6] = (short)f2bf(a1.z); afrag[7] = (short)f2bf(a1.w);
    float4v zero = {0.f, 0.f, 0.f, 0.f};
    float4v acc[3];
    #pragma unroll
    for (int ct = 0; ct < 3; ++ct) {
        short8 bfrag = *(const short8*)(web + (size_t)(ct * 16 + m) * EDGE_F + kq);
        acc[ct] = __builtin_amdgcn_mfma_f32_16x16x32_bf16(afrag, bfrag, zero, 0, 0, 0);
    }
    #pragma unroll
    for (int ct = 0; ct < 3; ++ct) {
        int oc = ct * 16 + m;
        int li = oc >> 3, hh = oc & 7;
        float bv = be[oc];
        #pragma unroll
        for (int r = 0; r < 4; ++r) {
            int row = (l >> 4) * 4 + r;
            float v = acc[ct][r] + bv;
            int pk8 = __builtin_amdgcn_cvt_pk_fp8_f32(v, v, 0, false);
            preE8[(size_t)li * NE * 8 + (size_t)(base + row) * 8 + hh] =
                (unsigned char)(pk8 & 0xff);
        }
    }
}

// ---------------------------------------------------------------- f32 -> bf16 (weights + x)
__global__ void tobf_all_kernel(const float* __restrict__ lin_w,
                                const float* __restrict__ x, ushort* __restrict__ wbhi,
                                ushort* __restrict__ xhi) {
    const int N1 = LAYERS * HDIM * HDIM;   // 393216
    const int N2 = N1 + NN * NODE_F;       // 1033216
    int i = blockIdx.x * 256 + threadIdx.x;
    if (i < N1) wbhi[i] = f2bf(lin_w[i]);
    else if (i < N2) xhi[i - N1] = f2bf(x[i - N1]);
}

// ---------------------------------------------------------------- pure-bf16 MFMA GEMM
// Writes fp8-e4m3 message table + attention logit partials a_src/a_dst
// (LOG2E-scaled). Bias (if any) is folded into the accumulators BEFORE both
// epilogues so logits include it exactly. Each 64-col block covers exactly
// 2 complete heads -> no atomics.
__global__ __launch_bounds__(128) void gemm_bf1(const ushort* __restrict__ Ah,
                                                const ushort* __restrict__ Bh,
                                                const float* __restrict__ bias,
                                                unsigned char* __restrict__ Cf8,
                                                const float* __restrict__ att_s,
                                                const float* __restrict__ att_d,
                                                float* __restrict__ a_src,
                                                float* __restrict__ a_dst,
                                                int N, int K) {
    __shared__ ushort sAh[64][40], sBh[64][40];
    int nb = blockIdx.y * 64, jb = blockIdx.x * 64;
    int t = threadIdx.x, w = t >> 6, l = t & 63;
    int srow = t >> 1, sq = (t & 1) * 16;
    int fr = l & 15, fq = (l >> 4) * 8;
    float4v acc[2][4] = {};
    for (int kt = 0; kt < K; kt += 32) {
        int gr = nb + srow;
        short8 a0 = {0,0,0,0,0,0,0,0}, a1 = {0,0,0,0,0,0,0,0};
        if (gr < N) {
            const short8* pa = (const short8*)(Ah + (size_t)gr * K + kt + sq);
            a0 = pa[0]; a1 = pa[1];
        }
        *(short8*)&sAh[srow][sq] = a0; *(short8*)&sAh[srow][sq + 8] = a1;
        const short8* pb = (const short8*)(Bh + (size_t)(jb + srow) * K + kt + sq);
        short8 b0 = pb[0], b1 = pb[1];
        *(short8*)&sBh[srow][sq] = b0; *(short8*)&sBh[srow][sq + 8] = b1;
        __syncthreads();
        short8 bh[4];
        #pragma unroll
        for (int nt = 0; nt < 4; ++nt)
            bh[nt] = *(const short8*)&sBh[nt * 16 + fr][fq];
        #pragma unroll
        for (int mt = 0; mt < 2; ++mt) {
            short8 ah = *(const short8*)&sAh[w * 32 + mt * 16 + fr][fq];
            #pragma unroll
            for (int nt = 0; nt < 4; ++nt)
                acc[mt][nt] = __builtin_amdgcn_mfma_f32_16x16x32_bf16(ah, bh[nt], acc[mt][nt], 0, 0, 0);
        }
        __syncthreads();
    }
    if (bias) {
        #pragma unroll
        for (int nt = 0; nt < 4; ++nt) {
            float bv = bias[jb + nt * 16 + fr];
            #pragma unroll
            for (int mt = 0; mt < 2; ++mt)
                #pragma unroll
                for (int r = 0; r < 4; ++r) acc[mt][nt][r] += bv;
        }
    }
    #pragma unroll
    for (int mt = 0; mt < 2; ++mt) {
        #pragma unroll
        for (int nt = 0; nt < 4; ++nt) {
            int col = jb + nt * 16 + fr;
            #pragma unroll
            for (int r = 0; r < 4; ++r) {
                int row = nb + w * 32 + mt * 16 + (l >> 4) * 4 + r;
                if (row < N) {
                    float v = acc[mt][nt][r];
                    int pk8 = __builtin_amdgcn_cvt_pk_fp8_f32(v, v, 0, false);
                    Cf8[(size_t)row * HDIM + col] = (unsigned char)(pk8 & 0xff);
                }
            }
        }
    }
    {
        int head0 = jb >> 5;
        float cs[4], cd[4];
        #pragma unroll
        for (int nt = 0; nt < 4; ++nt) {
            cs[nt] = att_s[jb + nt * 16 + fr] * LOG2E;
            cd[nt] = att_d[jb + nt * 16 + fr] * LOG2E;
        }
        #pragma unroll
        for (int mt = 0; mt < 2; ++mt) {
            #pragma unroll
            for (int r = 0; r < 4; ++r) {
                float s0 = acc[mt][0][r] * cs[0] + acc[mt][1][r] * cs[1];
                float s1 = acc[mt][2][r] * cs[2] + acc[mt][3][r] * cs[3];
                float d0 = acc[mt][0][r] * cd[0] + acc[mt][1][r] * cd[1];
                float d1 = acc[mt][2][r] * cd[2] + acc[mt][3][r] * cd[3];
                #pragma unroll
                for (int off = 8; off >= 1; off >>= 1) {
                    s0 += __shfl_xor(s0, off, 16);
                    s1 += __shfl_xor(s1, off, 16);
                    d0 += __shfl_xor(d0, off, 16);
                    d1 += __shfl_xor(d1, off, 16);
                }
                if (fr == 0) {
                    int row = nb + w * 32 + mt * 16 + (l >> 4) * 4 + r;
                    if (row < N) {
                        a_src[row * 8 + head0]     = s0;
                        a_src[row * 8 + head0 + 1] = s1;
                        a_dst[row * 8 + head0]     = d0;
                        a_dst[row * 8 + head0 + 1] = d1;
                    }
                }
            }
        }
    }
}

__device__ __forceinline__ float gelu_exact(float x) {
    return 0.5f * x * (1.f + erff(x * 0.70710678118654752f));
}

// ---------------------------------------------------------------- fused single-pass node kernel
// ONE NODE PER 128-THREAD BLOCK, edge range split across 2 waves (interleaved
// 8-edge groups); partial den/acc/psum combined via one LDS exchange + barrier.
// fp8 message table AND fp8 logit table (both L2-resident), transposed logit
// computation, in-register preL, bf16 residual stream.
__global__ __launch_bounds__(128) void node_kernel(const unsigned char* __restrict__ xwf8,
                                                  const unsigned char* __restrict__ pb,
                                                  const float* __restrict__ a_src,
                                                  const float* __restrict__ a_dst,
                                                  const int* __restrict__ row_ptr,
                                                  const int2* __restrict__ csr_se,
                                                  const ushort* __restrict__ hp,
                                                  ushort* __restrict__ hout,
                                                  const float* __restrict__ cb,
                                                  const float* __restrict__ lg,
                                                  const float* __restrict__ lb, int first) {
    __shared__ float red[6][128];
    int t = threadIdx.x;
    int wv = t >> 6, l = t & 63;
    int n = blockIdx.x;
    int start = row_ptr[n], end = row_ptr[n + 1];
    int hc = l >> 3;
    int hc8 = l & 56;
    int jj = l & 7;
    float adnh = a_dst[n * 8 + hc];
    const unsigned char* xb = xwf8 + 4 * l;

    float den = 0.f, acc[4] = {0.f, 0.f, 0.f, 0.f};
    float psum = 0.f;
    for (int idx = start + wv * 8; idx < end; idx += 16) {
        int myi = idx + jj;
        bool valid = myi < end;
        int2 se = valid ? csr_se[myi] : make_int2(n, 0);
        int snj[8];
        #pragma unroll
        for (int j = 0; j < 8; ++j) snj[j] = __shfl(se.x, hc8 + j, 64);
        unsigned g[8];
        #pragma unroll
        for (int j = 0; j < 8; ++j) g[j] = *(const unsigned*)(xb + (size_t)snj[j] * HDIM);
        float w_t = 0.f;
        if (valid) {
            unsigned pu = pb[(size_t)se.y * 8 + hc];
            floatx2 pd = __builtin_amdgcn_cvt_pk_f32_fp8(pu, false);
            float p_t = pd.x;
            float a_t = a_src[(size_t)se.x * 8 + hc] + adnh + p_t;
            w_t = exp2f(fminf(fmaxf(a_t, 0.2f * a_t), 57.7f));
            psum += p_t;
        }
        #pragma unroll
        for (int j = 0; j < 8; ++j) {
            float wj = __shfl(w_t, hc8 + j, 64);
            floatx2 lo = __builtin_amdgcn_cvt_pk_f32_fp8(g[j], false);
            floatx2 hi = __builtin_amdgcn_cvt_pk_f32_fp8(g[j], true);
            den += wj;
            acc[0] += wj * lo.x;
            acc[1] += wj * lo.y;
            acc[2] += wj * hi.x;
            acc[3] += wj * hi.y;
        }
    }
    // per-wave psum reduce within each 8-lane head group
    #pragma unroll
    for (int off = 1; off < 8; off <<= 1) psum += __shfl_xor(psum, off, 64);
    // cross-wave combine (one LDS exchange)
    red[0][t] = den; red[1][t] = acc[0]; red[2][t] = acc[1];
    red[3][t] = acc[2]; red[4][t] = acc[3]; red[5][t] = psum;
    __syncthreads();
    int ot = t ^ 64;
    den += red[0][ot]; acc[0] += red[1][ot]; acc[1] += red[2][ot];
    acc[2] += red[3][ot]; acc[3] += red[4][ot]; psum += red[5][ot];

    int deg = end - start;
    float preLv = deg > 0 ? psum / (float)deg : 0.f;
    // self loop (after combine, computed redundantly by both waves)
    {
        float al = a_src[n * 8 + hc] + adnh + preLv;
        al = fminf(fmaxf(al, 0.2f * al), 57.7f);
        float wself = exp2f(al);
        den += wself;
        unsigned gs = *(const unsigned*)(xb + (size_t)n * HDIM);
        floatx2 lo = __builtin_amdgcn_cvt_pk_f32_fp8(gs, false);
        floatx2 hi = __builtin_amdgcn_cvt_pk_f32_fp8(gs, true);
        acc[0] += wself * lo.x;
        acc[1] += wself * lo.y;
        acc[2] += wself * hi.x;
        acc[3] += wself * hi.y;
    }
    float4 cb4 = *(const float4*)(cb + 4 * l);
    float invh = 1.f / (den + 1e-16f);
    acc[0] = acc[0] * invh + cb4.x;
    acc[1] = acc[1] * invh + cb4.y;
    acc[2] = acc[2] * invh + cb4.z;
    acc[3] = acc[3] * invh + cb4.w;

    // LayerNorm over 256 channels (within each wave; both waves hold identical state)
    float part = acc[0] + acc[1] + acc[2] + acc[3];
    #pragma unroll
    for (int off = 32; off >= 1; off >>= 1) part += __shfl_xor(part, off, 64);
    float mu = part * (1.f / 256.f);
    float p2 = 0.f;
    #pragma unroll
    for (int j = 0; j < 4; ++j) {
        float d = acc[j] - mu;
        p2 += d * d;
    }
    #pragma unroll
    for (int off = 32; off >= 1; off >>= 1) p2 += __shfl_xor(p2, off, 64);
    float rstd = rsqrtf(p2 * (1.f / 256.f) + 1e-5f);

    if (wv == 0) {
        float4 lg4 = *(const float4*)(lg + 4 * l);
        float4 lb4 = *(const float4*)(lb + 4 * l);
        float o4[4];
        float lgv[4] = {lg4.x, lg4.y, lg4.z, lg4.w};
        float lbv[4] = {lb4.x, lb4.y, lb4.z, lb4.w};
        float hpv[4] = {0.f, 0.f, 0.f, 0.f};
        if (!first) {
            uint2 ph = *(const uint2*)(hp + (size_t)n * HDIM + 4 * l);
            hpv[0] = bf2f((ushort)(ph.x & 0xffff));
            hpv[1] = bf2f((ushort)(ph.x >> 16));
            hpv[2] = bf2f((ushort)(ph.y & 0xffff));
            hpv[3] = bf2f((ushort)(ph.y >> 16));
        }
        #pragma unroll
        for (int j = 0; j < 4; ++j) {
            float y = (acc[j] - mu) * rstd * lgv[j] + lbv[j];
            o4[j] = gelu_exact(y) + hpv[j];
        }
        uint2 po;
        po.x = (unsigned)f2bf(o4[0]) | ((unsigned)f2bf(o4[1]) << 16);
        po.y = (unsigned)f2bf(o4[2]) | ((unsigned)f2bf(o4[3]) << 16);
        *(uint2*)(hout + (size_t)n * HDIM + 4 * l) = po;
    }
}

// ---------------------------------------------------------------- graph readout (bf16 h)
// per-block register accumulation over 64 consecutive nodes -> ~40K atomics,
// 157 parallel blocks (NOT 32-block fused readout: 1.3% occupancy, +170us in r13)
__global__ __launch_bounds__(256) void graph_sum_kernel(const ushort* __restrict__ h,
                                                        const int* __restrict__ batch,
                                                        float* __restrict__ sums) {
    int t = threadIdx.x;
    int n0 = blockIdx.x * 64;
    int n1 = min(NN, n0 + 64);
    float acc = 0.f;
    int cur = batch[n0];
    for (int n = n0; n < n1; ++n) {
        int b = batch[n];
        if (b != cur) {
            atomicAdd(&sums[cur * HDIM + t], acc);
            acc = 0.f;
            cur = b;
        }
        acc += bf2f(h[(size_t)n * HDIM + t]);
    }
    atomicAdd(&sums[cur * HDIM + t], acc);
}

__device__ __forceinline__ int lower_bound_dev(const int* a, int n, int v) {
    int lo = 0, hi = n;
    while (lo < hi) {
        int mid = (lo + hi) >> 1;
        if (a[mid] < v) lo = mid + 1; else hi = mid;
    }
    return lo;
}

// fused 3-layer MLP head: one block per (graph, which), reads precomputed sums
__global__ __launch_bounds__(256) void mlp_kernel(const float* __restrict__ sums,
                                                  const int* __restrict__ batch,
                                                  const float* __restrict__ pw1,
                                                  const float* __restrict__ pb1,
                                                  const float* __restrict__ pw2,
                                                  const float* __restrict__ pb2,
                                                  const float* __restrict__ pw3,
                                                  const float* __restrict__ pb3,
                                                  const float* __restrict__ mw1,
                                                  const float* __restrict__ mb1,
                                                  const float* __restrict__ mw2,
                                                  const float* __restrict__ mb2,
                                                  const float* __restrict__ mw3,
                                                  const float* __restrict__ mb3,
                                                  float* __restrict__ out) {
    int g = blockIdx.x, which = blockIdx.y;
    const float* w1 = which ? mw1 : pw1; const float* b1 = which ? mb1 : pb1;
    const float* w2 = which ? mw2 : pw2; const float* b2 = which ? mb2 : pb2;
    const float* w3 = which ? mw3 : pw3; const float* b3 = which ? mb3 : pb3;
    __shared__ float xg[512];
    __shared__ float h1[256];
    __shared__ float h2[128];
    __shared__ float cinv_s;
    int t = threadIdx.x;
    if (t == 0) {
        int s0 = lower_bound_dev(batch, NN, g), s1 = lower_bound_dev(batch, NN, g + 1);
        cinv_s = 1.f / fmaxf((float)(s1 - s0), 1.f);
    }
    __syncthreads();
    float sv = sums[g * HDIM + t];
    xg[t] = sv * cinv_s;
    xg[256 + t] = sv;
    __syncthreads();
    {
        const float* wr = w1 + (size_t)t * 512;
        float acc = 0.f;
        #pragma unroll 8
        for (int k = 0; k < 512; k += 4) {
            float4 wv = *(const float4*)(wr + k);
            acc += wv.x * xg[k] + wv.y * xg[k + 1] + wv.z * xg[k + 2] + wv.w * xg[k + 3];
        }
        h1[t] = gelu_exact(acc + b1[t]);
    }
    __syncthreads();
    {
        int row = t >> 1, hf = t & 1;
        const float* wr = w2 + (size_t)row * 256 + hf * 128;
        const float* hx = h1 + hf * 128;
        float acc = 0.f;
        #pragma unroll 8
        for (int k = 0; k < 128; k += 4) {
            float4 wv = *(const float4*)(wr + k);
            acc += wv.x * hx[k] + wv.y * hx[k + 1] + wv.z * hx[k + 2] + wv.w * hx[k + 3];
        }
        acc += __shfl_xor(acc, 1, 64);
        if (hf == 0) h2[row] = gelu_exact(acc + b2[row]);
    }
    __syncthreads();
    if (t < 64) {
        float v0 = h2[t], v1 = h2[64 + t];
        #pragma unroll
        for (int o = 0; o < 3; ++o) {
            float p = w3[o * 128 + t] * v0 + w3[o * 128 + 64 + t] * v1;
            #pragma unroll
            for (int off = 32; off >= 1; off >>= 1) p += __shfl_xor(p, off, 64);
            if (t == 0) out[which * (NG * 3) + g * 3 + o] = 1.f / (1.f + expf(-(p + b3[o])));
        }
    }
}

// ---------------------------------------------------------------- launch
extern "C" void kernel_launch(void* const* d_in, const int* in_sizes, int n_in, void* d_out,
                              int out_size, void* d_ws, size_t ws_size, hipStream_t stream) {
    const float* x         = (const float*)d_in[0];
    const int*   ei        = (const int*)d_in[1];
    const int*   src       = ei;
    const int*   dst       = ei + NE;
    const float* edge_attr = (const float*)d_in[2];
    const int*   batch     = (const int*)d_in[3];
    const float* node_w    = (const float*)d_in[4];
    const float* node_b    = (const float*)d_in[5];
    const float* eew       = (const float*)d_in[6];
    const float* eeb       = (const float*)d_in[7];
    const float* lin_w     = (const float*)d_in[8];
    const float* att_src   = (const float*)d_in[9];
    const float* att_dst   = (const float*)d_in[10];
    const float* att_edge  = (const float*)d_in[11];
    const float* lin_edge_w= (const float*)d_in[12];
    const float* conv_b    = (const float*)d_in[13];
    const float* ln_g      = (const float*)d_in[14];
    const float* ln_b      = (const float*)d_in[15];
    const float* pw1 = (const float*)d_in[16]; const float* pb1 = (const float*)d_in[17];
    const float* pw2 = (const float*)d_in[18]; const float* pb2 = (const float*)d_in[19];
    const float* pw3 = (const float*)d_in[20]; const float* pb3 = (const float*)d_in[21];
    const float* mw1 = (const float*)d_in[22]; const float* mb1 = (const float*)d_in[23];
    const float* mw2 = (const float*)d_in[24]; const float* mb2 = (const float*)d_in[25];
    const float* mw3 = (const float*)d_in[26]; const float* mb3 = (const float*)d_in[27];
    float* out = (float*)d_out;

    float* wsf = (float*)d_ws;
    float* a_src     = wsf; wsf += (size_t)NN * HEADS;
    float* a_dst     = wsf; wsf += (size_t)NN * HEADS;
    float* bebuf     = wsf; wsf += 64;
    float* b0p       = wsf; wsf += HDIM;
    ushort* ubuf = (ushort*)wsf;
    ushort* webbf = ubuf; ubuf += (size_t)NOUT * EDGE_F;
    ushort* hb0  = ubuf; ubuf += (size_t)NN * HDIM;    // bf16 residual stream A
    ushort* hb1  = ubuf; ubuf += (size_t)NN * HDIM;    // bf16 residual stream B
    ushort* wbhi = ubuf; ubuf += (size_t)LAYERS * HDIM * HDIM;
    ushort* xhi  = ubuf; ubuf += (size_t)NN * NODE_F;
    ushort* w0p  = ubuf; ubuf += (size_t)HDIM * NODE_F;
    unsigned char* cbuf = (unsigned char*)ubuf;
    unsigned char* preE8 = cbuf; cbuf += (size_t)NE * NOUT;   // [LAYERS][NE][8] fp8
    unsigned char* xwf8  = cbuf; cbuf += (size_t)NN * HDIM;
    cbuf += ((size_t)cbuf & 7) ? (8 - ((size_t)cbuf & 7)) : 0;  // 8B-align
    int* ibuf    = (int*)cbuf;
    int* cnt     = ibuf; ibuf += NN + 16;
    float* sums  = (float*)ibuf; ibuf += NG * HDIM;  // adjacent to cnt -> one memset
    int* row_ptr = ibuf; ibuf += NN + 16;
    int* pos     = ibuf; ibuf += NN + 16;
    int2* csr_se = (int2*)ibuf; ibuf += 2 * NE;      // offset even -> 8B aligned

    // one memset covers cnt+sums
    hipMemsetAsync(cnt, 0, (NN + 16 + NG * HDIM) * sizeof(int), stream);

    // fold edge-attention weights (LOG2E-scaled); preE = streaming MFMA + fused degree count
    prep_kernel<<<LAYERS * HEADS, 256, 0, stream>>>(att_edge, lin_edge_w, eew, eeb, webbf, bebuf);
    preE_kernel<<<NE / 64, 256, 0, stream>>>(edge_attr, webbf, bebuf, preE8, dst, cnt);

    // CSR build (index-only)
    scan_kernel<<<1, 1024, 0, stream>>>(cnt, row_ptr, pos);
    scatter_kernel<<<(NE + 255) / 256, 256, 0, stream>>>(src, dst, pos, csr_se);

    // GEMM operand prep + embedding fold (W0p = lin_w[0]@node_w, b0p = lin_w[0]@node_b)
    {
        const int total = LAYERS * HDIM * HDIM + NN * NODE_F;
        tobf_all_kernel<<<(total + 255) / 256, 256, 0, stream>>>(lin_w, x, wbhi, xhi);
    }
    fold0_kernel<<<HDIM, 64, 0, stream>>>(lin_w, node_w, node_b, w0p, b0p);

    ushort* hb[2] = {hb0, hb1};
    for (int i = 0; i < LAYERS; ++i) {
        dim3 grid(HDIM / 64, (NN + 63) / 64);
        const ushort* Ain = (i == 0) ? xhi : hb[(i - 1) & 1];
        const ushort* Bin = (i == 0) ? w0p : wbhi + (size_t)i * HDIM * HDIM;
        int Kin = (i == 0) ? NODE_F : HDIM;
        const float* bias = (i == 0) ? b0p : nullptr;
        gemm_bf1<<<grid, 128, 0, stream>>>(Ain, Bin, bias, xwf8,
                                           att_src + i * HEADS * 32, att_dst + i * HEADS * 32,
                                           a_src, a_dst, NN, Kin);
        node_kernel<<<NN, 128, 0, stream>>>(
            xwf8, preE8 + (size_t)i * NE * 8, a_src, a_dst,
            row_ptr, csr_se, (i == 0) ? nullptr : hb[(i - 1) & 1], hb[i & 1],
            conv_b + i * HDIM, ln_g + i * HDIM, ln_b + i * HDIM, i == 0 ? 1 : 0);
    }

    graph_sum_kernel<<<(NN + 63) / 64, 256, 0, stream>>>(hb[(LAYERS - 1) & 1], batch, sums);
    {
        dim3 gm(NG, 2);
        mlp_kernel<<<gm, 256, 0, stream>>>(sums, batch, pw1, pb1, pw2, pb2, pw3, pb3,
                                           mw1, mb1, mw2, mb2, mw3, mb3, out);
    }
}

// Round 15
// 457.264 us; speedup vs baseline: 1.2864x; 1.0148x over previous
//
#include <hip/hip_runtime.h>
#include <math.h>

#define NN 10000
#define NE 320000
#define NODE_F 64
#define EDGE_F 32
#define HDIM 256
#define HEADS 8
#define LAYERS 6
#define NG 16
#define NOUT 48 // LAYERS*HEADS
#define LOG2E 1.4426950408889634f

typedef __attribute__((ext_vector_type(8))) short short8;
typedef __attribute__((ext_vector_type(4))) float float4v;
typedef __attribute__((ext_vector_type(2))) float floatx2;

// ---------------------------------------------------------------- CSR scan
// shuffle-based scan: 1024 threads, 2 barriers total
__global__ void scan_kernel(const int* __restrict__ cnt, int* __restrict__ row_ptr,
                            int* __restrict__ pos) {
    __shared__ int wsum[16];
    __shared__ int woff[16];
    int t = threadIdx.x;
    int lane = t & 63, wid = t >> 6;
    const int chunk = 10;                 // 1024*10 >= NN
    int lo = t * chunk;
    int loc[10];
    int s = 0;
    #pragma unroll
    for (int k = 0; k < 10; ++k) {
        int i = lo + k;
        int v = (i < NN) ? cnt[i] : 0;
        loc[k] = v;
        s += v;
    }
    int inc = s;
    #pragma unroll
    for (int off = 1; off < 64; off <<= 1) {
        int v = __shfl_up(inc, off, 64);
        if (lane >= off) inc += v;
    }
    if (lane == 63) wsum[wid] = inc;
    __syncthreads();
    if (t < 16) {
        int inc2 = wsum[t];
        #pragma unroll
        for (int off = 1; off < 16; off <<= 1) {
            int u = __shfl_up(inc2, off, 16);
            if (t >= off) inc2 += u;
        }
        woff[t] = inc2;
    }
    __syncthreads();
    int base = inc - s + (wid ? woff[wid - 1] : 0);
    #pragma unroll
    for (int k = 0; k < 10; ++k) {
        int i = lo + k;
        if (i < NN) {
            row_ptr[i] = base;
            pos[i] = base;
            base += loc[k];
        }
    }
    if (t == 1023) row_ptr[NN] = woff[15];
}

// index-only CSR scatter: csr_se[idx] = {src[e], e}. 8B random writes into a
// 2.56 MB (L2-resident) buffer — payloads are NOT permuted.
__global__ void scatter_kernel(const int* __restrict__ src, const int* __restrict__ dst,
                               int* __restrict__ pos, int2* __restrict__ csr_se) {
    int e = blockIdx.x * 256 + threadIdx.x;
    if (e >= NE) return;
    int d = dst[e];
    int idx = atomicAdd(&pos[d], 1);
    csr_se[idx] = make_int2(src[e], e);
}

// ---------------------------------------------------------------- bf16 helpers
__device__ __forceinline__ ushort f2bf(float f) {
    union { float f; unsigned u; } v; v.f = f;
    unsigned u = v.u;
    return (ushort)((u + 0x7fffu + ((u >> 16) & 1u)) >> 16);
}
__device__ __forceinline__ float bf2f(ushort b) {
    union { unsigned u; float f; } v; v.u = ((unsigned)b) << 16; return v.f;
}

// ---------------------------------------------------------------- fused setup kernel
// blocks 0..47:        edge-attn weight fold (LOG2E-scaled, bf16)
// blocks 48..303:      embedding fold W0p = lin_w[0]@node_w, b0p = lin_w[0]@node_b
// blocks 304..:        grid-stride f32->bf16 of lin_w and x
__global__ __launch_bounds__(256) void setup_kernel(const float* __restrict__ att_edge,
                                                    const float* __restrict__ lin_edge_w,
                                                    const float* __restrict__ eew,
                                                    const float* __restrict__ eeb,
                                                    ushort* __restrict__ webbf,
                                                    float* __restrict__ bebuf,
                                                    const float* __restrict__ lin_w,
                                                    const float* __restrict__ node_w,
                                                    const float* __restrict__ node_b,
                                                    ushort* __restrict__ w0p,
                                                    float* __restrict__ b0p,
                                                    const float* __restrict__ x,
                                                    ushort* __restrict__ wbhi,
                                                    ushort* __restrict__ xhi,
                                                    int nblk) {
    __shared__ float vsh[HDIM];
    int t = threadIdx.x;
    int b = blockIdx.x;
    if (b < LAYERS * HEADS) {
        int ih = b;
        int i = ih >> 3, h = ih & 7;
        float s = 0.f;
        const float* ae = att_edge + ih * 32;
        const float* lw = lin_edge_w + ((size_t)i * HDIM + h * 32) * HDIM + t;
        #pragma unroll
        for (int o = 0; o < 32; ++o) s += ae[o] * lw[(size_t)o * HDIM];
        vsh[t] = s;
        __syncthreads();
        if (t < EDGE_F) {
            float acc = 0.f;
            for (int k = 0; k < HDIM; ++k) acc += vsh[k] * eew[k * EDGE_F + t];
            webbf[ih * EDGE_F + t] = f2bf(acc * LOG2E);
        } else if (t == EDGE_F) {
            float acc = 0.f;
            for (int k = 0; k < HDIM; ++k) acc += vsh[k] * eeb[k];
            bebuf[ih] = acc * LOG2E;
        }
    } else if (b < LAYERS * HEADS + HDIM) {
        if (t < 64) {
            int j = b - LAYERS * HEADS, f = t;
            const float* wr = lin_w + (size_t)j * HDIM;
            float acc = 0.f, accb = 0.f;
            for (int k = 0; k < HDIM; ++k) acc += wr[k] * node_w[k * NODE_F + f];
            #pragma unroll
            for (int m = 0; m < 4; ++m) {
                int k = f + 64 * m;
                accb += wr[k] * node_b[k];
            }
            w0p[j * NODE_F + f] = f2bf(acc);
            #pragma unroll
            for (int off = 32; off >= 1; off >>= 1) accb += __shfl_xor(accb, off, 64);
            if (f == 0) b0p[j] = accb;
        }
    } else {
        const int N1 = LAYERS * HDIM * HDIM;   // 393216
        const int N2 = N1 + NN * NODE_F;       // 1033216
        int base = LAYERS * HEADS + HDIM;
        for (int i = (b - base) * 256 + t; i < N2; i += (nblk - base) * 256) {
            if (i < N1) wbhi[i] = f2bf(lin_w[i]);
            else xhi[i - N1] = f2bf(x[i - N1]);
        }
    }
}

// ---------------------------------------------------------------- preE via MFMA (+ degree count)
// Pure streaming: read edge_attr in e-order (coalesced f32), write
// preE8[li][e][8] sequentially as fp8-e4m3 (LOG2E-scaled logits; small
// magnitudes -> small ABSOLUTE error, which is what exp2 cares about).
// Threads 0..63 also count in-degrees for the CSR build.
__global__ __launch_bounds__(256) void preE_kernel(const float* __restrict__ edge_attr,
                                                   const ushort* __restrict__ web,
                                                   const float* __restrict__ be,
                                                   unsigned char* __restrict__ preE8,
                                                   const int* __restrict__ dst,
                                                   int* __restrict__ cnt) {
    int t = threadIdx.x;
    if (t < 64) atomicAdd(&cnt[dst[blockIdx.x * 64 + t]], 1);
    int wv = t >> 6, l = t & 63;
    int base = blockIdx.x * 64 + wv * 16;   // NE % 64 == 0
    int m = l & 15, kq = (l >> 4) * 8;
    const float* ar = edge_attr + (size_t)(base + m) * EDGE_F + kq;
    float4 a0 = *(const float4*)(ar);
    float4 a1 = *(const float4*)(ar + 4);
    short8 afrag;
    afrag[0] = (short)f2bf(a0.x); afrag[1] = (short)f2bf(a0.y);
    afrag[2] = (short)f2bf(a0.z); afrag[3] = (short)f2bf(a0.w);
    afrag[4] = (short)f2bf(a1.x); afrag[5] = (short)f2bf(a1.y);
    afrag[6] = (short)f2bf(a1.z); afrag[7] = (short)f2bf(a1.w);
    float4v zero = {0.f, 0.f, 0.f, 0.f};
    float4v acc[3];
    #pragma unroll
    for (int ct = 0; ct < 3; ++ct) {
        short8 bfrag = *(const short8*)(web + (size_t)(ct * 16 + m) * EDGE_F + kq);
        acc[ct] = __builtin_amdgcn_mfma_f32_16x16x32_bf16(afrag, bfrag, zero, 0, 0, 0);
    }
    #pragma unroll
    for (int ct = 0; ct < 3; ++ct) {
        int oc = ct * 16 + m;
        int li = oc >> 3, hh = oc & 7;
        float bv = be[oc];
        #pragma unroll
        for (int r = 0; r < 4; ++r) {
            int row = (l >> 4) * 4 + r;
            float v = acc[ct][r] + bv;
            int pk8 = __builtin_amdgcn_cvt_pk_fp8_f32(v, v, 0, false);
            preE8[(size_t)li * NE * 8 + (size_t)(base + row) * 8 + hh] =
                (unsigned char)(pk8 & 0xff);
        }
    }
}

// ---------------------------------------------------------------- pure-bf16 MFMA GEMM
// 128x64 tile, 256 threads (4 waves x 32-row subtile). Writes fp8-e4m3 message
// table + attention logit partials a_src/a_dst (LOG2E-scaled). Bias folded into
// accumulators BEFORE both epilogues. Each 64-col block covers exactly 2
// complete heads -> no atomics.
__global__ __launch_bounds__(256) void gemm_bf1(const ushort* __restrict__ Ah,
                                                const ushort* __restrict__ Bh,
                                                const float* __restrict__ bias,
                                                unsigned char* __restrict__ Cf8,
                                                const float* __restrict__ att_s,
                                                const float* __restrict__ att_d,
                                                float* __restrict__ a_src,
                                                float* __restrict__ a_dst,
                                                int N, int K) {
    __shared__ ushort sAh[128][40];
    __shared__ ushort sBh[64][40];
    int nb = blockIdx.y * 128, jb = blockIdx.x * 64;
    int t = threadIdx.x, w = t >> 6, l = t & 63;
    int arow = t >> 1, asq = (t & 1) * 16;   // A: 2 threads/row, 16 shorts each
    int brow = t >> 2, bsq = (t & 3) * 8;    // B: 4 threads/row, 8 shorts each
    int fr = l & 15, fq = (l >> 4) * 8;
    float4v acc[2][4] = {};
    for (int kt = 0; kt < K; kt += 32) {
        int gr = nb + arow;
        short8 a0 = {0,0,0,0,0,0,0,0}, a1 = {0,0,0,0,0,0,0,0};
        if (gr < N) {
            const short8* pa = (const short8*)(Ah + (size_t)gr * K + kt + asq);
            a0 = pa[0]; a1 = pa[1];
        }
        *(short8*)&sAh[arow][asq] = a0; *(short8*)&sAh[arow][asq + 8] = a1;
        short8 b0 = *(const short8*)(Bh + (size_t)(jb + brow) * K + kt + bsq);
        *(short8*)&sBh[brow][bsq] = b0;
        __syncthreads();
        short8 bh[4];
        #pragma unroll
        for (int nt = 0; nt < 4; ++nt)
            bh[nt] = *(const short8*)&sBh[nt * 16 + fr][fq];
        #pragma unroll
        for (int mt = 0; mt < 2; ++mt) {
            short8 ah = *(const short8*)&sAh[w * 32 + mt * 16 + fr][fq];
            #pragma unroll
            for (int nt = 0; nt < 4; ++nt)
                acc[mt][nt] = __builtin_amdgcn_mfma_f32_16x16x32_bf16(ah, bh[nt], acc[mt][nt], 0, 0, 0);
        }
        __syncthreads();
    }
    if (bias) {
        #pragma unroll
        for (int nt = 0; nt < 4; ++nt) {
            float bv = bias[jb + nt * 16 + fr];
            #pragma unroll
            for (int mt = 0; mt < 2; ++mt)
                #pragma unroll
                for (int r = 0; r < 4; ++r) acc[mt][nt][r] += bv;
        }
    }
    #pragma unroll
    for (int mt = 0; mt < 2; ++mt) {
        #pragma unroll
        for (int nt = 0; nt < 4; ++nt) {
            int col = jb + nt * 16 + fr;
            #pragma unroll
            for (int r = 0; r < 4; ++r) {
                int row = nb + w * 32 + mt * 16 + (l >> 4) * 4 + r;
                if (row < N) {
                    float v = acc[mt][nt][r];
                    int pk8 = __builtin_amdgcn_cvt_pk_fp8_f32(v, v, 0, false);
                    Cf8[(size_t)row * HDIM + col] = (unsigned char)(pk8 & 0xff);
                }
            }
        }
    }
    {
        int head0 = jb >> 5;
        float cs[4], cd[4];
        #pragma unroll
        for (int nt = 0; nt < 4; ++nt) {
            cs[nt] = att_s[jb + nt * 16 + fr] * LOG2E;
            cd[nt] = att_d[jb + nt * 16 + fr] * LOG2E;
        }
        #pragma unroll
        for (int mt = 0; mt < 2; ++mt) {
            #pragma unroll
            for (int r = 0; r < 4; ++r) {
                float s0 = acc[mt][0][r] * cs[0] + acc[mt][1][r] * cs[1];
                float s1 = acc[mt][2][r] * cs[2] + acc[mt][3][r] * cs[3];
                float d0 = acc[mt][0][r] * cd[0] + acc[mt][1][r] * cd[1];
                float d1 = acc[mt][2][r] * cd[2] + acc[mt][3][r] * cd[3];
                #pragma unroll
                for (int off = 8; off >= 1; off >>= 1) {
                    s0 += __shfl_xor(s0, off, 16);
                    s1 += __shfl_xor(s1, off, 16);
                    d0 += __shfl_xor(d0, off, 16);
                    d1 += __shfl_xor(d1, off, 16);
                }
                if (fr == 0) {
                    int row = nb + w * 32 + mt * 16 + (l >> 4) * 4 + r;
                    if (row < N) {
                        a_src[row * 8 + head0]     = s0;
                        a_src[row * 8 + head0 + 1] = s1;
                        a_dst[row * 8 + head0]     = d0;
                        a_dst[row * 8 + head0 + 1] = d1;
                    }
                }
            }
        }
    }
}

__device__ __forceinline__ float gelu_exact(float x) {
    return 0.5f * x * (1.f + erff(x * 0.70710678118654752f));
}

// ---------------------------------------------------------------- fused single-pass node kernel
// ONE NODE PER 128-THREAD BLOCK, edge range split across 2 waves (interleaved
// 8-edge groups); partial den/acc/psum combined via one LDS exchange + barrier.
// fp8 message table AND fp8 logit table (both L2-resident), transposed logit
// computation, in-register preL, bf16 residual stream.
__global__ __launch_bounds__(128) void node_kernel(const unsigned char* __restrict__ xwf8,
                                                  const unsigned char* __restrict__ pb,
                                                  const float* __restrict__ a_src,
                                                  const float* __restrict__ a_dst,
                                                  const int* __restrict__ row_ptr,
                                                  const int2* __restrict__ csr_se,
                                                  const ushort* __restrict__ hp,
                                                  ushort* __restrict__ hout,
                                                  const float* __restrict__ cb,
                                                  const float* __restrict__ lg,
                                                  const float* __restrict__ lb, int first) {
    __shared__ float red[6][128];
    int t = threadIdx.x;
    int wv = t >> 6, l = t & 63;
    int n = blockIdx.x;
    int start = row_ptr[n], end = row_ptr[n + 1];
    int hc = l >> 3;
    int hc8 = l & 56;
    int jj = l & 7;
    float adnh = a_dst[n * 8 + hc];
    const unsigned char* xb = xwf8 + 4 * l;

    float den = 0.f, acc[4] = {0.f, 0.f, 0.f, 0.f};
    float psum = 0.f;
    for (int idx = start + wv * 8; idx < end; idx += 16) {
        int myi = idx + jj;
        bool valid = myi < end;
        int2 se = valid ? csr_se[myi] : make_int2(n, 0);
        int snj[8];
        #pragma unroll
        for (int j = 0; j < 8; ++j) snj[j] = __shfl(se.x, hc8 + j, 64);
        unsigned g[8];
        #pragma unroll
        for (int j = 0; j < 8; ++j) g[j] = *(const unsigned*)(xb + (size_t)snj[j] * HDIM);
        float w_t = 0.f;
        if (valid) {
            unsigned pu = pb[(size_t)se.y * 8 + hc];
            floatx2 pd = __builtin_amdgcn_cvt_pk_f32_fp8(pu, false);
            float p_t = pd.x;
            float a_t = a_src[(size_t)se.x * 8 + hc] + adnh + p_t;
            w_t = exp2f(fminf(fmaxf(a_t, 0.2f * a_t), 57.7f));
            psum += p_t;
        }
        #pragma unroll
        for (int j = 0; j < 8; ++j) {
            float wj = __shfl(w_t, hc8 + j, 64);
            floatx2 lo = __builtin_amdgcn_cvt_pk_f32_fp8(g[j], false);
            floatx2 hi = __builtin_amdgcn_cvt_pk_f32_fp8(g[j], true);
            den += wj;
            acc[0] += wj * lo.x;
            acc[1] += wj * lo.y;
            acc[2] += wj * hi.x;
            acc[3] += wj * hi.y;
        }
    }
    // per-wave psum reduce within each 8-lane head group
    #pragma unroll
    for (int off = 1; off < 8; off <<= 1) psum += __shfl_xor(psum, off, 64);
    // cross-wave combine (one LDS exchange)
    red[0][t] = den; red[1][t] = acc[0]; red[2][t] = acc[1];
    red[3][t] = acc[2]; red[4][t] = acc[3]; red[5][t] = psum;
    __syncthreads();
    int ot = t ^ 64;
    den += red[0][ot]; acc[0] += red[1][ot]; acc[1] += red[2][ot];
    acc[2] += red[3][ot]; acc[3] += red[4][ot]; psum += red[5][ot];

    int deg = end - start;
    float preLv = deg > 0 ? psum / (float)deg : 0.f;
    // self loop (after combine, computed redundantly by both waves)
    {
        float al = a_src[n * 8 + hc] + adnh + preLv;
        al = fminf(fmaxf(al, 0.2f * al), 57.7f);
        float wself = exp2f(al);
        den += wself;
        unsigned gs = *(const unsigned*)(xb + (size_t)n * HDIM);
        floatx2 lo = __builtin_amdgcn_cvt_pk_f32_fp8(gs, false);
        floatx2 hi = __builtin_amdgcn_cvt_pk_f32_fp8(gs, true);
        acc[0] += wself * lo.x;
        acc[1] += wself * lo.y;
        acc[2] += wself * hi.x;
        acc[3] += wself * hi.y;
    }
    float4 cb4 = *(const float4*)(cb + 4 * l);
    float invh = 1.f / (den + 1e-16f);
    acc[0] = acc[0] * invh + cb4.x;
    acc[1] = acc[1] * invh + cb4.y;
    acc[2] = acc[2] * invh + cb4.z;
    acc[3] = acc[3] * invh + cb4.w;

    // LayerNorm over 256 channels (within each wave; both waves hold identical state)
    float part = acc[0] + acc[1] + acc[2] + acc[3];
    #pragma unroll
    for (int off = 32; off >= 1; off >>= 1) part += __shfl_xor(part, off, 64);
    float mu = part * (1.f / 256.f);
    float p2 = 0.f;
    #pragma unroll
    for (int j = 0; j < 4; ++j) {
        float d = acc[j] - mu;
        p2 += d * d;
    }
    #pragma unroll
    for (int off = 32; off >= 1; off >>= 1) p2 += __shfl_xor(p2, off, 64);
    float rstd = rsqrtf(p2 * (1.f / 256.f) + 1e-5f);

    if (wv == 0) {
        float4 lg4 = *(const float4*)(lg + 4 * l);
        float4 lb4 = *(const float4*)(lb + 4 * l);
        float o4[4];
        float lgv[4] = {lg4.x, lg4.y, lg4.z, lg4.w};
        float lbv[4] = {lb4.x, lb4.y, lb4.z, lb4.w};
        float hpv[4] = {0.f, 0.f, 0.f, 0.f};
        if (!first) {
            uint2 ph = *(const uint2*)(hp + (size_t)n * HDIM + 4 * l);
            hpv[0] = bf2f((ushort)(ph.x & 0xffff));
            hpv[1] = bf2f((ushort)(ph.x >> 16));
            hpv[2] = bf2f((ushort)(ph.y & 0xffff));
            hpv[3] = bf2f((ushort)(ph.y >> 16));
        }
        #pragma unroll
        for (int j = 0; j < 4; ++j) {
            float y = (acc[j] - mu) * rstd * lgv[j] + lbv[j];
            o4[j] = gelu_exact(y) + hpv[j];
        }
        uint2 po;
        po.x = (unsigned)f2bf(o4[0]) | ((unsigned)f2bf(o4[1]) << 16);
        po.y = (unsigned)f2bf(o4[2]) | ((unsigned)f2bf(o4[3]) << 16);
        *(uint2*)(hout + (size_t)n * HDIM + 4 * l) = po;
    }
}

// ---------------------------------------------------------------- graph readout (bf16 h)
// per-block register accumulation over 64 consecutive nodes -> ~40K atomics,
// 157 parallel blocks (NOT 32-block fused readout: 1.3% occupancy, +170us in r13)
__global__ __launch_bounds__(256) void graph_sum_kernel(const ushort* __restrict__ h,
                                                        const int* __restrict__ batch,
                                                        float* __restrict__ sums) {
    int t = threadIdx.x;
    int n0 = blockIdx.x * 64;
    int n1 = min(NN, n0 + 64);
    float acc = 0.f;
    int cur = batch[n0];
    for (int n = n0; n < n1; ++n) {
        int b = batch[n];
        if (b != cur) {
            atomicAdd(&sums[cur * HDIM + t], acc);
            acc = 0.f;
            cur = b;
        }
        acc += bf2f(h[(size_t)n * HDIM + t]);
    }
    atomicAdd(&sums[cur * HDIM + t], acc);
}

__device__ __forceinline__ int lower_bound_dev(const int* a, int n, int v) {
    int lo = 0, hi = n;
    while (lo < hi) {
        int mid = (lo + hi) >> 1;
        if (a[mid] < v) lo = mid + 1; else hi = mid;
    }
    return lo;
}

// fused 3-layer MLP head: one block per (graph, which), reads precomputed sums
__global__ __launch_bounds__(256) void mlp_kernel(const float* __restrict__ sums,
                                                  const int* __restrict__ batch,
                                                  const float* __restrict__ pw1,
                                                  const float* __restrict__ pb1,
                                                  const float* __restrict__ pw2,
                                                  const float* __restrict__ pb2,
                                                  const float* __restrict__ pw3,
                                                  const float* __restrict__ pb3,
                                                  const float* __restrict__ mw1,
                                                  const float* __restrict__ mb1,
                                                  const float* __restrict__ mw2,
                                                  const float* __restrict__ mb2,
                                                  const float* __restrict__ mw3,
                                                  const float* __restrict__ mb3,
                                                  float* __restrict__ out) {
    int g = blockIdx.x, which = blockIdx.y;
    const float* w1 = which ? mw1 : pw1; const float* b1 = which ? mb1 : pb1;
    const float* w2 = which ? mw2 : pw2; const float* b2 = which ? mb2 : pb2;
    const float* w3 = which ? mw3 : pw3; const float* b3 = which ? mb3 : pb3;
    __shared__ float xg[512];
    __shared__ float h1[256];
    __shared__ float h2[128];
    __shared__ float cinv_s;
    int t = threadIdx.x;
    if (t == 0) {
        int s0 = lower_bound_dev(batch, NN, g), s1 = lower_bound_dev(batch, NN, g + 1);
        cinv_s = 1.f / fmaxf((float)(s1 - s0), 1.f);
    }
    __syncthreads();
    float sv = sums[g * HDIM + t];
    xg[t] = sv * cinv_s;
    xg[256 + t] = sv;
    __syncthreads();
    {
        const float* wr = w1 + (size_t)t * 512;
        float acc = 0.f;
        #pragma unroll 8
        for (int k = 0; k < 512; k += 4) {
            float4 wv = *(const float4*)(wr + k);
            acc += wv.x * xg[k] + wv.y * xg[k + 1] + wv.z * xg[k + 2] + wv.w * xg[k + 3];
        }
        h1[t] = gelu_exact(acc + b1[t]);
    }
    __syncthreads();
    {
        int row = t >> 1, hf = t & 1;
        const float* wr = w2 + (size_t)row * 256 + hf * 128;
        const float* hx = h1 + hf * 128;
        float acc = 0.f;
        #pragma unroll 8
        for (int k = 0; k < 128; k += 4) {
            float4 wv = *(const float4*)(wr + k);
            acc += wv.x * hx[k] + wv.y * hx[k + 1] + wv.z * hx[k + 2] + wv.w * hx[k + 3];
        }
        acc += __shfl_xor(acc, 1, 64);
        if (hf == 0) h2[row] = gelu_exact(acc + b2[row]);
    }
    __syncthreads();
    if (t < 64) {
        float v0 = h2[t], v1 = h2[64 + t];
        #pragma unroll
        for (int o = 0; o < 3; ++o) {
            float p = w3[o * 128 + t] * v0 + w3[o * 128 + 64 + t] * v1;
            #pragma unroll
            for (int off = 32; off >= 1; off >>= 1) p += __shfl_xor(p, off, 64);
            if (t == 0) out[which * (NG * 3) + g * 3 + o] = 1.f / (1.f + expf(-(p + b3[o])));
        }
    }
}

// ---------------------------------------------------------------- launch
extern "C" void kernel_launch(void* const* d_in, const int* in_sizes, int n_in, void* d_out,
                              int out_size, void* d_ws, size_t ws_size, hipStream_t stream) {
    const float* x         = (const float*)d_in[0];
    const int*   ei        = (const int*)d_in[1];
    const int*   src       = ei;
    const int*   dst       = ei + NE;
    const float* edge_attr = (const float*)d_in[2];
    const int*   batch     = (const int*)d_in[3];
    const float* node_w    = (const float*)d_in[4];
    const float* node_b    = (const float*)d_in[5];
    const float* eew       = (const float*)d_in[6];
    const float* eeb       = (const float*)d_in[7];
    const float* lin_w     = (const float*)d_in[8];
    const float* att_src   = (const float*)d_in[9];
    const float* att_dst   = (const float*)d_in[10];
    const float* att_edge  = (const float*)d_in[11];
    const float* lin_edge_w= (const float*)d_in[12];
    const float* conv_b    = (const float*)d_in[13];
    const float* ln_g      = (const float*)d_in[14];
    const float* ln_b      = (const float*)d_in[15];
    const float* pw1 = (const float*)d_in[16]; const float* pb1 = (const float*)d_in[17];
    const float* pw2 = (const float*)d_in[18]; const float* pb2 = (const float*)d_in[19];
    const float* pw3 = (const float*)d_in[20]; const float* pb3 = (const float*)d_in[21];
    const float* mw1 = (const float*)d_in[22]; const float* mb1 = (const float*)d_in[23];
    const float* mw2 = (const float*)d_in[24]; const float* mb2 = (const float*)d_in[25];
    const float* mw3 = (const float*)d_in[26]; const float* mb3 = (const float*)d_in[27];
    float* out = (float*)d_out;

    float* wsf = (float*)d_ws;
    float* a_src     = wsf; wsf += (size_t)NN * HEADS;
    float* a_dst     = wsf; wsf += (size_t)NN * HEADS;
    float* bebuf     = wsf; wsf += 64;
    float* b0p       = wsf; wsf += HDIM;
    ushort* ubuf = (ushort*)wsf;
    ushort* webbf = ubuf; ubuf += (size_t)NOUT * EDGE_F;
    ushort* hb0  = ubuf; ubuf += (size_t)NN * HDIM;    // bf16 residual stream A
    ushort* hb1  = ubuf; ubuf += (size_t)NN * HDIM;    // bf16 residual stream B
    ushort* wbhi = ubuf; ubuf += (size_t)LAYERS * HDIM * HDIM;
    ushort* xhi  = ubuf; ubuf += (size_t)NN * NODE_F;
    ushort* w0p  = ubuf; ubuf += (size_t)HDIM * NODE_F;
    unsigned char* cbuf = (unsigned char*)ubuf;
    unsigned char* preE8 = cbuf; cbuf += (size_t)NE * NOUT;   // [LAYERS][NE][8] fp8
    unsigned char* xwf8  = cbuf; cbuf += (size_t)NN * HDIM;
    cbuf += ((size_t)cbuf & 7) ? (8 - ((size_t)cbuf & 7)) : 0;  // 8B-align
    int* ibuf    = (int*)cbuf;
    int* cnt     = ibuf; ibuf += NN + 16;
    float* sums  = (float*)ibuf; ibuf += NG * HDIM;  // adjacent to cnt -> one memset
    int* row_ptr = ibuf; ibuf += NN + 16;
    int* pos     = ibuf; ibuf += NN + 16;
    int2* csr_se = (int2*)ibuf; ibuf += 2 * NE;      // offset even -> 8B aligned

    // one memset covers cnt+sums
    hipMemsetAsync(cnt, 0, (NN + 16 + NG * HDIM) * sizeof(int), stream);

    // fused setup (edge-attn fold + embedding fold + bf16 conversions)
    const int SETUP_BLK = LAYERS * HEADS + HDIM + 1024;   // 48 + 256 + 1024
    setup_kernel<<<SETUP_BLK, 256, 0, stream>>>(att_edge, lin_edge_w, eew, eeb, webbf, bebuf,
                                                lin_w, node_w, node_b, w0p, b0p,
                                                x, wbhi, xhi, SETUP_BLK);
    // preE = streaming MFMA + fused degree count
    preE_kernel<<<NE / 64, 256, 0, stream>>>(edge_attr, webbf, bebuf, preE8, dst, cnt);

    // CSR build (index-only)
    scan_kernel<<<1, 1024, 0, stream>>>(cnt, row_ptr, pos);
    scatter_kernel<<<(NE + 255) / 256, 256, 0, stream>>>(src, dst, pos, csr_se);

    ushort* hb[2] = {hb0, hb1};
    for (int i = 0; i < LAYERS; ++i) {
        dim3 grid(HDIM / 64, (NN + 127) / 128);
        const ushort* Ain = (i == 0) ? xhi : hb[(i - 1) & 1];
        const ushort* Bin = (i == 0) ? w0p : wbhi + (size_t)i * HDIM * HDIM;
        int Kin = (i == 0) ? NODE_F : HDIM;
        const float* bias = (i == 0) ? b0p : nullptr;
        gemm_bf1<<<grid, 256, 0, stream>>>(Ain, Bin, bias, xwf8,
                                           att_src + i * HEADS * 32, att_dst + i * HEADS * 32,
                                           a_src, a_dst, NN, Kin);
        node_kernel<<<NN, 128, 0, stream>>>(
            xwf8, preE8 + (size_t)i * NE * 8, a_src, a_dst,
            row_ptr, csr_se, (i == 0) ? nullptr : hb[(i - 1) & 1], hb[i & 1],
            conv_b + i * HDIM, ln_g + i * HDIM, ln_b + i * HDIM, i == 0 ? 1 : 0);
    }

    graph_sum_kernel<<<(NN + 63) / 64, 256, 0, stream>>>(hb[(LAYERS - 1) & 1], batch, sums);
    {
        dim3 gm(NG, 2);
        mlp_kernel<<<gm, 256, 0, stream>>>(sums, batch, pw1, pb1, pw2, pb2, pw3, pb3,
                                           mw1, mb1, mw2, mb2, mw3, mb3, out);
    }
}

// Round 17
// 449.773 us; speedup vs baseline: 1.3078x; 1.0167x over previous
//
#include <hip/hip_runtime.h>
#include <math.h>

#define NN 10000
#define NE 320000
#define NODE_F 64
#define EDGE_F 32
#define HDIM 256
#define HEADS 8
#define LAYERS 6
#define NG 16
#define NPB 4   // nodes per node_kernel block, ONE wave per node, no coupling
#define NOUT 48 // LAYERS*HEADS
#define LOG2E 1.4426950408889634f

typedef __attribute__((ext_vector_type(8))) short short8;
typedef __attribute__((ext_vector_type(4))) float float4v;
typedef __attribute__((ext_vector_type(2))) float floatx2;

// ---------------------------------------------------------------- CSR scan
// shuffle-based scan: 1024 threads, 2 barriers total
__global__ void scan_kernel(const int* __restrict__ cnt, int* __restrict__ row_ptr,
                            int* __restrict__ pos) {
    __shared__ int wsum[16];
    __shared__ int woff[16];
    int t = threadIdx.x;
    int lane = t & 63, wid = t >> 6;
    const int chunk = 10;                 // 1024*10 >= NN
    int lo = t * chunk;
    int loc[10];
    int s = 0;
    #pragma unroll
    for (int k = 0; k < 10; ++k) {
        int i = lo + k;
        int v = (i < NN) ? cnt[i] : 0;
        loc[k] = v;
        s += v;
    }
    int inc = s;
    #pragma unroll
    for (int off = 1; off < 64; off <<= 1) {
        int v = __shfl_up(inc, off, 64);
        if (lane >= off) inc += v;
    }
    if (lane == 63) wsum[wid] = inc;
    __syncthreads();
    if (t < 16) {
        int inc2 = wsum[t];
        #pragma unroll
        for (int off = 1; off < 16; off <<= 1) {
            int u = __shfl_up(inc2, off, 16);
            if (t >= off) inc2 += u;
        }
        woff[t] = inc2;
    }
    __syncthreads();
    int base = inc - s + (wid ? woff[wid - 1] : 0);
    #pragma unroll
    for (int k = 0; k < 10; ++k) {
        int i = lo + k;
        if (i < NN) {
            row_ptr[i] = base;
            pos[i] = base;
            base += loc[k];
        }
    }
    if (t == 1023) row_ptr[NN] = woff[15];
}

// index-only CSR scatter: csr_se[idx] = {src[e], e}. 8B random writes into a
// 2.56 MB (L2-resident) buffer — payloads are NOT permuted.
__global__ void scatter_kernel(const int* __restrict__ src, const int* __restrict__ dst,
                               int* __restrict__ pos, int2* __restrict__ csr_se) {
    int e = blockIdx.x * 256 + threadIdx.x;
    if (e >= NE) return;
    int d = dst[e];
    int idx = atomicAdd(&pos[d], 1);
    csr_se[idx] = make_int2(src[e], e);
}

// ---------------------------------------------------------------- bf16 helpers
__device__ __forceinline__ ushort f2bf(float f) {
    union { float f; unsigned u; } v; v.f = f;
    unsigned u = v.u;
    return (ushort)((u + 0x7fffu + ((u >> 16) & 1u)) >> 16);
}
__device__ __forceinline__ float bf2f(ushort b) {
    union { unsigned u; float f; } v; v.u = ((unsigned)b) << 16; return v.f;
}

// ---------------------------------------------------------------- fused setup kernel
// blocks 0..47:        edge-attn weight fold (LOG2E-scaled, bf16)
// blocks 48..303:      embedding fold W0p = lin_w[0]@node_w, b0p = lin_w[0]@node_b
// blocks 304..:        grid-stride f32->bf16 of lin_w and x
__global__ __launch_bounds__(256) void setup_kernel(const float* __restrict__ att_edge,
                                                    const float* __restrict__ lin_edge_w,
                                                    const float* __restrict__ eew,
                                                    const float* __restrict__ eeb,
                                                    ushort* __restrict__ webbf,
                                                    float* __restrict__ bebuf,
                                                    const float* __restrict__ lin_w,
                                                    const float* __restrict__ node_w,
                                                    const float* __restrict__ node_b,
                                                    ushort* __restrict__ w0p,
                                                    float* __restrict__ b0p,
                                                    const float* __restrict__ x,
                                                    ushort* __restrict__ wbhi,
                                                    ushort* __restrict__ xhi,
                                                    int nblk) {
    __shared__ float vsh[HDIM];
    int t = threadIdx.x;
    int b = blockIdx.x;
    if (b < LAYERS * HEADS) {
        int ih = b;
        int i = ih >> 3, h = ih & 7;
        float s = 0.f;
        const float* ae = att_edge + ih * 32;
        const float* lw = lin_edge_w + ((size_t)i * HDIM + h * 32) * HDIM + t;
        #pragma unroll
        for (int o = 0; o < 32; ++o) s += ae[o] * lw[(size_t)o * HDIM];
        vsh[t] = s;
        __syncthreads();
        if (t < EDGE_F) {
            float acc = 0.f;
            for (int k = 0; k < HDIM; ++k) acc += vsh[k] * eew[k * EDGE_F + t];
            webbf[ih * EDGE_F + t] = f2bf(acc * LOG2E);
        } else if (t == EDGE_F) {
            float acc = 0.f;
            for (int k = 0; k < HDIM; ++k) acc += vsh[k] * eeb[k];
            bebuf[ih] = acc * LOG2E;
        }
    } else if (b < LAYERS * HEADS + HDIM) {
        if (t < 64) {
            int j = b - LAYERS * HEADS, f = t;
            const float* wr = lin_w + (size_t)j * HDIM;
            float acc = 0.f, accb = 0.f;
            for (int k = 0; k < HDIM; ++k) acc += wr[k] * node_w[k * NODE_F + f];
            #pragma unroll
            for (int m = 0; m < 4; ++m) {
                int k = f + 64 * m;
                accb += wr[k] * node_b[k];
            }
            w0p[j * NODE_F + f] = f2bf(acc);
            #pragma unroll
            for (int off = 32; off >= 1; off >>= 1) accb += __shfl_xor(accb, off, 64);
            if (f == 0) b0p[j] = accb;
        }
    } else {
        const int N1 = LAYERS * HDIM * HDIM;   // 393216
        const int N2 = N1 + NN * NODE_F;       // 1033216
        int base = LAYERS * HEADS + HDIM;
        for (int i = (b - base) * 256 + t; i < N2; i += (nblk - base) * 256) {
            if (i < N1) wbhi[i] = f2bf(lin_w[i]);
            else xhi[i - N1] = f2bf(x[i - N1]);
        }
    }
}

// ---------------------------------------------------------------- preE via MFMA (+ degree count)
// Pure streaming: read edge_attr in e-order (coalesced f32), write
// preE8[li][e][8] sequentially as fp8-e4m3 (LOG2E-scaled logits; small
// magnitudes -> small ABSOLUTE error, which is what exp2 cares about).
// Threads 0..63 also count in-degrees for the CSR build.
__global__ __launch_bounds__(256) void preE_kernel(const float* __restrict__ edge_attr,
                                                   const ushort* __restrict__ web,
                                                   const float* __restrict__ be,
                                                   unsigned char* __restrict__ preE8,
                                                   const int* __restrict__ dst,
                                                   int* __restrict__ cnt) {
    int t = threadIdx.x;
    if (t < 64) atomicAdd(&cnt[dst[blockIdx.x * 64 + t]], 1);
    int wv = t >> 6, l = t & 63;
    int base = blockIdx.x * 64 + wv * 16;   // NE % 64 == 0
    int m = l & 15, kq = (l >> 4) * 8;
    const float* ar = edge_attr + (size_t)(base + m) * EDGE_F + kq;
    float4 a0 = *(const float4*)(ar);
    float4 a1 = *(const float4*)(ar + 4);
    short8 afrag;
    afrag[0] = (short)f2bf(a0.x); afrag[1] = (short)f2bf(a0.y);
    afrag[2] = (short)f2bf(a0.z); afrag[3] = (short)f2bf(a0.w);
    afrag[4] = (short)f2bf(a1.x); afrag[5] = (short)f2bf(a1.y);
    afrag[6] = (short)f2bf(a1.z); afrag[7] = (short)f2bf(a1.w);
    float4v zero = {0.f, 0.f, 0.f, 0.f};
    float4v acc[3];
    #pragma unroll
    for (int ct = 0; ct < 3; ++ct) {
        short8 bfrag = *(const short8*)(web + (size_t)(ct * 16 + m) * EDGE_F + kq);
        acc[ct] = __builtin_amdgcn_mfma_f32_16x16x32_bf16(afrag, bfrag, zero, 0, 0, 0);
    }
    #pragma unroll
    for (int ct = 0; ct < 3; ++ct) {
        int oc = ct * 16 + m;
        int li = oc >> 3, hh = oc & 7;
        float bv = be[oc];
        #pragma unroll
        for (int r = 0; r < 4; ++r) {
            int row = (l >> 4) * 4 + r;
            float v = acc[ct][r] + bv;
            int pk8 = __builtin_amdgcn_cvt_pk_fp8_f32(v, v, 0, false);
            preE8[(size_t)li * NE * 8 + (size_t)(base + row) * 8 + hh] =
                (unsigned char)(pk8 & 0xff);
        }
    }
}

// ---------------------------------------------------------------- pure-bf16 MFMA GEMM
// 128x64 tile, 256 threads (4 waves x 32-row subtile). Writes fp8-e4m3 message
// table + attention logit partials a_src/a_dst (LOG2E-scaled). Bias folded into
// accumulators BEFORE both epilogues. Each 64-col block covers exactly 2
// complete heads -> no atomics.
__global__ __launch_bounds__(256) void gemm_bf1(const ushort* __restrict__ Ah,
                                                const ushort* __restrict__ Bh,
                                                const float* __restrict__ bias,
                                                unsigned char* __restrict__ Cf8,
                                                const float* __restrict__ att_s,
                                                const float* __restrict__ att_d,
                                                float* __restrict__ a_src,
                                                float* __restrict__ a_dst,
                                                int N, int K) {
    __shared__ ushort sAh[128][40];
    __shared__ ushort sBh[64][40];
    int nb = blockIdx.y * 128, jb = blockIdx.x * 64;
    int t = threadIdx.x, w = t >> 6, l = t & 63;
    int arow = t >> 1, asq = (t & 1) * 16;   // A: 2 threads/row, 16 shorts each
    int brow = t >> 2, bsq = (t & 3) * 8;    // B: 4 threads/row, 8 shorts each
    int fr = l & 15, fq = (l >> 4) * 8;
    float4v acc[2][4] = {};
    for (int kt = 0; kt < K; kt += 32) {
        int gr = nb + arow;
        short8 a0 = {0,0,0,0,0,0,0,0}, a1 = {0,0,0,0,0,0,0,0};
        if (gr < N) {
            const short8* pa = (const short8*)(Ah + (size_t)gr * K + kt + asq);
            a0 = pa[0]; a1 = pa[1];
        }
        *(short8*)&sAh[arow][asq] = a0; *(short8*)&sAh[arow][asq + 8] = a1;
        short8 b0 = *(const short8*)(Bh + (size_t)(jb + brow) * K + kt + bsq);
        *(short8*)&sBh[brow][bsq] = b0;
        __syncthreads();
        short8 bh[4];
        #pragma unroll
        for (int nt = 0; nt < 4; ++nt)
            bh[nt] = *(const short8*)&sBh[nt * 16 + fr][fq];
        #pragma unroll
        for (int mt = 0; mt < 2; ++mt) {
            short8 ah = *(const short8*)&sAh[w * 32 + mt * 16 + fr][fq];
            #pragma unroll
            for (int nt = 0; nt < 4; ++nt)
                acc[mt][nt] = __builtin_amdgcn_mfma_f32_16x16x32_bf16(ah, bh[nt], acc[mt][nt], 0, 0, 0);
        }
        __syncthreads();
    }
    if (bias) {
        #pragma unroll
        for (int nt = 0; nt < 4; ++nt) {
            float bv = bias[jb + nt * 16 + fr];
            #pragma unroll
            for (int mt = 0; mt < 2; ++mt)
                #pragma unroll
                for (int r = 0; r < 4; ++r) acc[mt][nt][r] += bv;
        }
    }
    #pragma unroll
    for (int mt = 0; mt < 2; ++mt) {
        #pragma unroll
        for (int nt = 0; nt < 4; ++nt) {
            int col = jb + nt * 16 + fr;
            #pragma unroll
            for (int r = 0; r < 4; ++r) {
                int row = nb + w * 32 + mt * 16 + (l >> 4) * 4 + r;
                if (row < N) {
                    float v = acc[mt][nt][r];
                    int pk8 = __builtin_amdgcn_cvt_pk_fp8_f32(v, v, 0, false);
                    Cf8[(size_t)row * HDIM + col] = (unsigned char)(pk8 & 0xff);
                }
            }
        }
    }
    {
        int head0 = jb >> 5;
        float cs[4], cd[4];
        #pragma unroll
        for (int nt = 0; nt < 4; ++nt) {
            cs[nt] = att_s[jb + nt * 16 + fr] * LOG2E;
            cd[nt] = att_d[jb + nt * 16 + fr] * LOG2E;
        }
        #pragma unroll
        for (int mt = 0; mt < 2; ++mt) {
            #pragma unroll
            for (int r = 0; r < 4; ++r) {
                float s0 = acc[mt][0][r] * cs[0] + acc[mt][1][r] * cs[1];
                float s1 = acc[mt][2][r] * cs[2] + acc[mt][3][r] * cs[3];
                float d0 = acc[mt][0][r] * cd[0] + acc[mt][1][r] * cd[1];
                float d1 = acc[mt][2][r] * cd[2] + acc[mt][3][r] * cd[3];
                #pragma unroll
                for (int off = 8; off >= 1; off >>= 1) {
                    s0 += __shfl_xor(s0, off, 16);
                    s1 += __shfl_xor(s1, off, 16);
                    d0 += __shfl_xor(d0, off, 16);
                    d1 += __shfl_xor(d1, off, 16);
                }
                if (fr == 0) {
                    int row = nb + w * 32 + mt * 16 + (l >> 4) * 4 + r;
                    if (row < N) {
                        a_src[row * 8 + head0]     = s0;
                        a_src[row * 8 + head0 + 1] = s1;
                        a_dst[row * 8 + head0]     = d0;
                        a_dst[row * 8 + head0 + 1] = d1;
                    }
                }
            }
        }
    }
}

__device__ __forceinline__ float gelu_exact(float x) {
    return 0.5f * x * (1.f + erff(x * 0.70710678118654752f));
}

// ---------------------------------------------------------------- fused single-pass node kernel
// ONE WAVE PER NODE, NPB=4 nodes per 256-thread block (2500 blocks -> lower
// dispatch ramp; no cross-wave coupling, no LDS). fp8 message table AND fp8
// logit table (both L2-resident), transposed logit computation, in-register
// preL, masked 8-wide loop, bf16 residual stream.
__global__ __launch_bounds__(64 * NPB) void node_kernel(const unsigned char* __restrict__ xwf8,
                                                  const unsigned char* __restrict__ pb,
                                                  const float* __restrict__ a_src,
                                                  const float* __restrict__ a_dst,
                                                  const int* __restrict__ row_ptr,
                                                  const int2* __restrict__ csr_se,
                                                  const ushort* __restrict__ hp,
                                                  ushort* __restrict__ hout,
                                                  const float* __restrict__ cb,
                                                  const float* __restrict__ lg,
                                                  const float* __restrict__ lb, int first) {
    int wv = threadIdx.x >> 6, l = threadIdx.x & 63;
    int n = blockIdx.x * NPB + wv;
    if (n >= NN) return;
    int start = row_ptr[n], end = row_ptr[n + 1];
    int hc = l >> 3;
    int hc8 = l & 56;
    int jj = l & 7;
    float adnh = a_dst[n * 8 + hc];
    const unsigned char* xb = xwf8 + 4 * l;

    float den = 0.f, acc[4] = {0.f, 0.f, 0.f, 0.f};
    float psum = 0.f;
    for (int idx = start; idx < end; idx += 8) {
        int myi = idx + jj;
        bool valid = myi < end;
        int2 se = valid ? csr_se[myi] : make_int2(n, 0);
        int snj[8];
        #pragma unroll
        for (int j = 0; j < 8; ++j) snj[j] = __shfl(se.x, hc8 + j, 64);
        unsigned g[8];
        #pragma unroll
        for (int j = 0; j < 8; ++j) g[j] = *(const unsigned*)(xb + (size_t)snj[j] * HDIM);
        float w_t = 0.f;
        if (valid) {
            unsigned pu = pb[(size_t)se.y * 8 + hc];
            floatx2 pd = __builtin_amdgcn_cvt_pk_f32_fp8(pu, false);
            float p_t = pd.x;
            float a_t = a_src[(size_t)se.x * 8 + hc] + adnh + p_t;
            w_t = exp2f(fminf(fmaxf(a_t, 0.2f * a_t), 57.7f));
            psum += p_t;
        }
        #pragma unroll
        for (int j = 0; j < 8; ++j) {
            float wj = __shfl(w_t, hc8 + j, 64);
            floatx2 lo = __builtin_amdgcn_cvt_pk_f32_fp8(g[j], false);
            floatx2 hi = __builtin_amdgcn_cvt_pk_f32_fp8(g[j], true);
            den += wj;
            acc[0] += wj * lo.x;
            acc[1] += wj * lo.y;
            acc[2] += wj * hi.x;
            acc[3] += wj * hi.y;
        }
    }
    // in-register preL: mean of this head's p over incoming edges
    #pragma unroll
    for (int off = 1; off < 8; off <<= 1) psum += __shfl_xor(psum, off, 64);
    int deg = end - start;
    float preLv = deg > 0 ? psum / (float)deg : 0.f;
    // self loop
    {
        float al = a_src[n * 8 + hc] + adnh + preLv;
        al = fminf(fmaxf(al, 0.2f * al), 57.7f);
        float wself = exp2f(al);
        den += wself;
        unsigned gs = *(const unsigned*)(xb + (size_t)n * HDIM);
        floatx2 lo = __builtin_amdgcn_cvt_pk_f32_fp8(gs, false);
        floatx2 hi = __builtin_amdgcn_cvt_pk_f32_fp8(gs, true);
        acc[0] += wself * lo.x;
        acc[1] += wself * lo.y;
        acc[2] += wself * hi.x;
        acc[3] += wself * hi.y;
    }
    float4 cb4 = *(const float4*)(cb + 4 * l);
    float invh = 1.f / (den + 1e-16f);
    acc[0] = acc[0] * invh + cb4.x;
    acc[1] = acc[1] * invh + cb4.y;
    acc[2] = acc[2] * invh + cb4.z;
    acc[3] = acc[3] * invh + cb4.w;

    // LayerNorm over 256 channels
    float part = acc[0] + acc[1] + acc[2] + acc[3];
    #pragma unroll
    for (int off = 32; off >= 1; off >>= 1) part += __shfl_xor(part, off, 64);
    float mu = part * (1.f / 256.f);
    float p2 = 0.f;
    #pragma unroll
    for (int j = 0; j < 4; ++j) {
        float d = acc[j] - mu;
        p2 += d * d;
    }
    #pragma unroll
    for (int off = 32; off >= 1; off >>= 1) p2 += __shfl_xor(p2, off, 64);
    float rstd = rsqrtf(p2 * (1.f / 256.f) + 1e-5f);

    float4 lg4 = *(const float4*)(lg + 4 * l);
    float4 lb4 = *(const float4*)(lb + 4 * l);
    float o4[4];
    float lgv[4] = {lg4.x, lg4.y, lg4.z, lg4.w};
    float lbv[4] = {lb4.x, lb4.y, lb4.z, lb4.w};
    float hpv[4] = {0.f, 0.f, 0.f, 0.f};
    if (!first) {
        uint2 ph = *(const uint2*)(hp + (size_t)n * HDIM + 4 * l);
        hpv[0] = bf2f((ushort)(ph.x & 0xffff));
        hpv[1] = bf2f((ushort)(ph.x >> 16));
        hpv[2] = bf2f((ushort)(ph.y & 0xffff));
        hpv[3] = bf2f((ushort)(ph.y >> 16));
    }
    #pragma unroll
    for (int j = 0; j < 4; ++j) {
        float y = (acc[j] - mu) * rstd * lgv[j] + lbv[j];
        o4[j] = gelu_exact(y) + hpv[j];
    }
    uint2 po;
    po.x = (unsigned)f2bf(o4[0]) | ((unsigned)f2bf(o4[1]) << 16);
    po.y = (unsigned)f2bf(o4[2]) | ((unsigned)f2bf(o4[3]) << 16);
    *(uint2*)(hout + (size_t)n * HDIM + 4 * l) = po;
}

// ---------------------------------------------------------------- graph readout (bf16 h)
// per-block register accumulation over 64 consecutive nodes -> ~40K atomics,
// 157 parallel blocks (NOT 32-block fused readout: 1.3% occupancy, +170us in r13)
__global__ __launch_bounds__(256) void graph_sum_kernel(const ushort* __restrict__ h,
                                                        const int* __restrict__ batch,
                                                        float* __restrict__ sums) {
    int t = threadIdx.x;
    int n0 = blockIdx.x * 64;
    int n1 = min(NN, n0 + 64);
    float acc = 0.f;
    int cur = batch[n0];
    for (int n = n0; n < n1; ++n) {
        int b = batch[n];
        if (b != cur) {
            atomicAdd(&sums[cur * HDIM + t], acc);
            acc = 0.f;
            cur = b;
        }
        acc += bf2f(h[(size_t)n * HDIM + t]);
    }
    atomicAdd(&sums[cur * HDIM + t], acc);
}

__device__ __forceinline__ int lower_bound_dev(const int* a, int n, int v) {
    int lo = 0, hi = n;
    while (lo < hi) {
        int mid = (lo + hi) >> 1;
        if (a[mid] < v) lo = mid + 1; else hi = mid;
    }
    return lo;
}

// fused 3-layer MLP head: one block per (graph, which), reads precomputed sums
__global__ __launch_bounds__(256) void mlp_kernel(const float* __restrict__ sums,
                                                  const int* __restrict__ batch,
                                                  const float* __restrict__ pw1,
                                                  const float* __restrict__ pb1,
                                                  const float* __restrict__ pw2,
                                                  const float* __restrict__ pb2,
                                                  const float* __restrict__ pw3,
                                                  const float* __restrict__ pb3,
                                                  const float* __restrict__ mw1,
                                                  const float* __restrict__ mb1,
                                                  const float* __restrict__ mw2,
                                                  const float* __restrict__ mb2,
                                                  const float* __restrict__ mw3,
                                                  const float* __restrict__ mb3,
                                                  float* __restrict__ out) {
    int g = blockIdx.x, which = blockIdx.y;
    const float* w1 = which ? mw1 : pw1; const float* b1 = which ? mb1 : pb1;
    const float* w2 = which ? mw2 : pw2; const float* b2 = which ? mb2 : pb2;
    const float* w3 = which ? mw3 : pw3; const float* b3 = which ? mb3 : pb3;
    __shared__ float xg[512];
    __shared__ float h1[256];
    __shared__ float h2[128];
    __shared__ float cinv_s;
    int t = threadIdx.x;
    if (t == 0) {
        int s0 = lower_bound_dev(batch, NN, g), s1 = lower_bound_dev(batch, NN, g + 1);
        cinv_s = 1.f / fmaxf((float)(s1 - s0), 1.f);
    }
    __syncthreads();
    float sv = sums[g * HDIM + t];
    xg[t] = sv * cinv_s;
    xg[256 + t] = sv;
    __syncthreads();
    {
        const float* wr = w1 + (size_t)t * 512;
        float acc = 0.f;
        #pragma unroll 8
        for (int k = 0; k < 512; k += 4) {
            float4 wv = *(const float4*)(wr + k);
            acc += wv.x * xg[k] + wv.y * xg[k + 1] + wv.z * xg[k + 2] + wv.w * xg[k + 3];
        }
        h1[t] = gelu_exact(acc + b1[t]);
    }
    __syncthreads();
    {
        int row = t >> 1, hf = t & 1;
        const float* wr = w2 + (size_t)row * 256 + hf * 128;
        const float* hx = h1 + hf * 128;
        float acc = 0.f;
        #pragma unroll 8
        for (int k = 0; k < 128; k += 4) {
            float4 wv = *(const float4*)(wr + k);
            acc += wv.x * hx[k] + wv.y * hx[k + 1] + wv.z * hx[k + 2] + wv.w * hx[k + 3];
        }
        acc += __shfl_xor(acc, 1, 64);
        if (hf == 0) h2[row] = gelu_exact(acc + b2[row]);
    }
    __syncthreads();
    if (t < 64) {
        float v0 = h2[t], v1 = h2[64 + t];
        #pragma unroll
        for (int o = 0; o < 3; ++o) {
            float p = w3[o * 128 + t] * v0 + w3[o * 128 + 64 + t] * v1;
            #pragma unroll
            for (int off = 32; off >= 1; off >>= 1) p += __shfl_xor(p, off, 64);
            if (t == 0) out[which * (NG * 3) + g * 3 + o] = 1.f / (1.f + expf(-(p + b3[o])));
        }
    }
}

// ---------------------------------------------------------------- launch
extern "C" void kernel_launch(void* const* d_in, const int* in_sizes, int n_in, void* d_out,
                              int out_size, void* d_ws, size_t ws_size, hipStream_t stream) {
    const float* x         = (const float*)d_in[0];
    const int*   ei        = (const int*)d_in[1];
    const int*   src       = ei;
    const int*   dst       = ei + NE;
    const float* edge_attr = (const float*)d_in[2];
    const int*   batch     = (const int*)d_in[3];
    const float* node_w    = (const float*)d_in[4];
    const float* node_b    = (const float*)d_in[5];
    const float* eew       = (const float*)d_in[6];
    const float* eeb       = (const float*)d_in[7];
    const float* lin_w     = (const float*)d_in[8];
    const float* att_src   = (const float*)d_in[9];
    const float* att_dst   = (const float*)d_in[10];
    const float* att_edge  = (const float*)d_in[11];
    const float* lin_edge_w= (const float*)d_in[12];
    const float* conv_b    = (const float*)d_in[13];
    const float* ln_g      = (const float*)d_in[14];
    const float* ln_b      = (const float*)d_in[15];
    const float* pw1 = (const float*)d_in[16]; const float* pb1 = (const float*)d_in[17];
    const float* pw2 = (const float*)d_in[18]; const float* pb2 = (const float*)d_in[19];
    const float* pw3 = (const float*)d_in[20]; const float* pb3 = (const float*)d_in[21];
    const float* mw1 = (const float*)d_in[22]; const float* mb1 = (const float*)d_in[23];
    const float* mw2 = (const float*)d_in[24]; const float* mb2 = (const float*)d_in[25];
    const float* mw3 = (const float*)d_in[26]; const float* mb3 = (const float*)d_in[27];
    float* out = (float*)d_out;

    float* wsf = (float*)d_ws;
    float* a_src     = wsf; wsf += (size_t)NN * HEADS;
    float* a_dst     = wsf; wsf += (size_t)NN * HEADS;
    float* bebuf     = wsf; wsf += 64;
    float* b0p       = wsf; wsf += HDIM;
    ushort* ubuf = (ushort*)wsf;
    ushort* webbf = ubuf; ubuf += (size_t)NOUT * EDGE_F;
    ushort* hb0  = ubuf; ubuf += (size_t)NN * HDIM;    // bf16 residual stream A
    ushort* hb1  = ubuf; ubuf += (size_t)NN * HDIM;    // bf16 residual stream B
    ushort* wbhi = ubuf; ubuf += (size_t)LAYERS * HDIM * HDIM;
    ushort* xhi  = ubuf; ubuf += (size_t)NN * NODE_F;
    ushort* w0p  = ubuf; ubuf += (size_t)HDIM * NODE_F;
    unsigned char* cbuf = (unsigned char*)ubuf;
    unsigned char* preE8 = cbuf; cbuf += (size_t)NE * NOUT;   // [LAYERS][NE][8] fp8
    unsigned char* xwf8  = cbuf; cbuf += (size_t)NN * HDIM;
    cbuf += ((size_t)cbuf & 7) ? (8 - ((size_t)cbuf & 7)) : 0;  // 8B-align
    int* ibuf    = (int*)cbuf;
    int* cnt     = ibuf; ibuf += NN + 16;
    float* sums  = (float*)ibuf; ibuf += NG * HDIM;  // adjacent to cnt -> one memset
    int* row_ptr = ibuf; ibuf += NN + 16;
    int* pos     = ibuf; ibuf += NN + 16;
    int2* csr_se = (int2*)ibuf; ibuf += 2 * NE;      // offset even -> 8B aligned

    // one memset covers cnt+sums
    hipMemsetAsync(cnt, 0, (NN + 16 + NG * HDIM) * sizeof(int), stream);

    // fused setup (edge-attn fold + embedding fold + bf16 conversions)
    const int SETUP_BLK = LAYERS * HEADS + HDIM + 1024;   // 48 + 256 + 1024
    setup_kernel<<<SETUP_BLK, 256, 0, stream>>>(att_edge, lin_edge_w, eew, eeb, webbf, bebuf,
                                                lin_w, node_w, node_b, w0p, b0p,
                                                x, wbhi, xhi, SETUP_BLK);
    // preE = streaming MFMA + fused degree count
    preE_kernel<<<NE / 64, 256, 0, stream>>>(edge_attr, webbf, bebuf, preE8, dst, cnt);

    // CSR build (index-only)
    scan_kernel<<<1, 1024, 0, stream>>>(cnt, row_ptr, pos);
    scatter_kernel<<<(NE + 255) / 256, 256, 0, stream>>>(src, dst, pos, csr_se);

    ushort* hb[2] = {hb0, hb1};
    for (int i = 0; i < LAYERS; ++i) {
        dim3 grid(HDIM / 64, (NN + 127) / 128);
        const ushort* Ain = (i == 0) ? xhi : hb[(i - 1) & 1];
        const ushort* Bin = (i == 0) ? w0p : wbhi + (size_t)i * HDIM * HDIM;
        int Kin = (i == 0) ? NODE_F : HDIM;
        const float* bias = (i == 0) ? b0p : nullptr;
        gemm_bf1<<<grid, 256, 0, stream>>>(Ain, Bin, bias, xwf8,
                                           att_src + i * HEADS * 32, att_dst + i * HEADS * 32,
                                           a_src, a_dst, NN, Kin);
        node_kernel<<<(NN + NPB - 1) / NPB, 64 * NPB, 0, stream>>>(
            xwf8, preE8 + (size_t)i * NE * 8, a_src, a_dst,
            row_ptr, csr_se, (i == 0) ? nullptr : hb[(i - 1) & 1], hb[i & 1],
            conv_b + i * HDIM, ln_g + i * HDIM, ln_b + i * HDIM, i == 0 ? 1 : 0);
    }

    graph_sum_kernel<<<(NN + 63) / 64, 256, 0, stream>>>(hb[(LAYERS - 1) & 1], batch, sums);
    {
        dim3 gm(NG, 2);
        mlp_kernel<<<gm, 256, 0, stream>>>(sums, batch, pw1, pb1, pw2, pb2, pw3, pb3,
                                           mw1, mb1, mw2, mb2, mw3, mb3, out);
    }
}